// Round 2
// baseline (283.893 us; speedup 1.0000x reference)
//
#include <hip/hip_runtime.h>
#include <stdint.h>

typedef unsigned short u16;
typedef unsigned int   u32;
typedef unsigned char  u8;
typedef __attribute__((ext_vector_type(4))) float f32x4;
typedef __attribute__((ext_vector_type(8))) __bf16 bf16x8;
typedef __attribute__((ext_vector_type(2))) unsigned int u32x2;
typedef __attribute__((ext_vector_type(4))) unsigned int u32x4;

#define MFMA16(a, b, c) __builtin_amdgcn_mfma_f32_16x16x32_bf16((a), (b), (c), 0, 0, 0)

__device__ __forceinline__ u16 f2bf(float f) {
  u32 u = __float_as_uint(f);
  return (u16)((u + 0x7fffu + ((u >> 16) & 1u)) >> 16);  // RNE
}

__device__ __forceinline__ void gl_lds16(const void* g, void* l) {
  __builtin_amdgcn_global_load_lds((const __attribute__((address_space(1))) u32*)g,
                                   (__attribute__((address_space(3))) u32*)l, 16, 0, 0);
}

// v_cvt_pk_bf16_f32: {lo=bf16(a), hi=bf16(b)} with RNE
__device__ __forceinline__ u32 cvtpk(float a, float b) {
  u32 r;
  asm("v_cvt_pk_bf16_f32 %0, %1, %2" : "=v"(r) : "v"(a), "v"(b));
  return r;
}

// swap lanes 32-63 of x with lanes 0-31 of y:
// x' = {x[0:32], y[0:32]},  y' = {x[32:64], y[32:64]}
__device__ __forceinline__ void plswap32(u32& x, u32& y) {
  u32x2 r = __builtin_amdgcn_permlane32_swap(x, y, false, false);
  x = r.x; y = r.y;
}
// swap 16-rows: x' = {x g0, y g0, x g2, y g2}, y' = {x g1, y g1, x g3, y g3}
__device__ __forceinline__ void plswap16(u32& x, u32& y) {
  u32x2 r = __builtin_amdgcn_permlane16_swap(x, y, false, false);
  x = r.x; y = r.y;
}

// reduce across the 4 lane-groups (lanes l15+16g, g=0..3); result in all lanes
__device__ __forceinline__ float redmax_lg(float v) {
  u32 x = __float_as_uint(v), y = x;
  plswap16(x, y);
  float m = fmaxf(__uint_as_float(x), __uint_as_float(y));
  u32 a = __float_as_uint(m), b = a;
  plswap32(a, b);
  return fmaxf(__uint_as_float(a), __uint_as_float(b));
}
__device__ __forceinline__ float redsum_lg(float v) {
  u32 x = __float_as_uint(v), y = x;
  plswap16(x, y);
  float m = __uint_as_float(x) + __uint_as_float(y);
  u32 a = __float_as_uint(m), b = a;
  plswap32(a, b);
  return __uint_as_float(a) + __uint_as_float(b);
}

// ---------------- f32 -> bf16 converters ----------------
__global__ void __launch_bounds__(256) cvt3_kernel(const float4* __restrict__ a, const float4* __restrict__ b,
                                                   const float4* __restrict__ c, ushort4* __restrict__ oa,
                                                   ushort4* __restrict__ ob, ushort4* __restrict__ oc, int n4) {
  int i = blockIdx.x * 256 + threadIdx.x;
  if (i >= n4) return;
  float4 v;
  v = a[i]; oa[i] = make_ushort4(f2bf(v.x), f2bf(v.y), f2bf(v.z), f2bf(v.w));
  v = b[i]; ob[i] = make_ushort4(f2bf(v.x), f2bf(v.y), f2bf(v.z), f2bf(v.w));
  v = c[i]; oc[i] = make_ushort4(f2bf(v.x), f2bf(v.y), f2bf(v.z), f2bf(v.w));
}

__global__ void __launch_bounds__(256) cvt4_kernel(const float4* __restrict__ a, const float4* __restrict__ b,
                                                   const float4* __restrict__ c, const float4* __restrict__ d,
                                                   ushort4* __restrict__ oa, ushort4* __restrict__ ob,
                                                   ushort4* __restrict__ oc, ushort4* __restrict__ od, int n4) {
  int i = blockIdx.x * 256 + threadIdx.x;
  if (i >= n4) return;
  float4 v;
  v = a[i]; oa[i] = make_ushort4(f2bf(v.x), f2bf(v.y), f2bf(v.z), f2bf(v.w));
  v = b[i]; ob[i] = make_ushort4(f2bf(v.x), f2bf(v.y), f2bf(v.z), f2bf(v.w));
  v = c[i]; oc[i] = make_ushort4(f2bf(v.x), f2bf(v.y), f2bf(v.z), f2bf(v.w));
  v = d[i]; od[i] = make_ushort4(f2bf(v.x), f2bf(v.y), f2bf(v.z), f2bf(v.w));
}

// ---------------- pack 5 boolean matrices into bytes, [b][q][k] (linear) ----------------
__device__ __forceinline__ u32 pbit(float t, float s, float d, float c, int m) {
  return (t != 0.0f ? 1u : 0u) | (s != 0.0f ? 2u : 0u) | (d != 0.0f ? 4u : 0u) |
         (c != 0.0f ? 8u : 0u) | (m != 0 ? 16u : 0u);
}

__global__ void __launch_bounds__(256) pack_kernel(const float4* __restrict__ tok, const float4* __restrict__ st,
                                                   const float4* __restrict__ df, const float4* __restrict__ cf,
                                                   const int4* __restrict__ msk, uint4* __restrict__ out) {
  int i = blockIdx.x * 256 + threadIdx.x;  // 16 elements per thread
  if (i >= 262144) return;
  u32 wds[4];
#pragma unroll
  for (int j = 0; j < 4; j++) {
    float4 vt = tok[i * 4 + j], vs = st[i * 4 + j], vd = df[i * 4 + j], vc = cf[i * 4 + j];
    int4 vm = msk[i * 4 + j];
    u32 b0 = pbit(vt.x, vs.x, vd.x, vc.x, vm.x);
    u32 b1 = pbit(vt.y, vs.y, vd.y, vc.y, vm.y);
    u32 b2 = pbit(vt.z, vs.z, vd.z, vc.z, vm.z);
    u32 b3 = pbit(vt.w, vs.w, vd.w, vc.w, vm.w);
    wds[j] = b0 | (b1 << 8) | (b2 << 16) | (b3 << 24);
  }
  out[i] = make_uint4(wds[0], wds[1], wds[2], wds[3]);
}

// ---------------- bf16 GEMM: C[m][n] = sum_k A[m][k]*W[n][k] + bias[n] ----------------
// MODE 0: write bf16 head-major  Qh/Kh[(b*16+h)*65536 + s*64 + d]
// MODE 2: write bf16 transposed  VhT[(b*16+h)*65536 + d*1024 + s]
// MODE 3: write f32 plain        out[m*1024 + n]
template <int MODE>
__global__ void __launch_bounds__(256) gemm_bt(const u16* __restrict__ A, const u16* __restrict__ W,
                                               const float* __restrict__ bias, void* __restrict__ Out) {
  __shared__ u16 smA[128 * 32];
  __shared__ u16 smB[128 * 32];
  const int t = threadIdx.x;
  const int w = t >> 6, l = t & 63;
  const int l15 = l & 15, lg = l >> 4;
  const int m0 = blockIdx.y * 128, n0 = blockIdx.x * 128;
  const int wr = w >> 1, wc = w & 1;
  f32x4 acc[4][4] = {};
  const int srow = w * 16 + (l >> 2);
  const int scol = (l & 3) * 8;
  const u16* Ab = A + (size_t)(m0 + srow) * 1024 + scol;
  const u16* Wb = W + (size_t)(n0 + srow) * 1024 + scol;
  u16* sA0 = smA + srow * 32 + scol;
  u16* sB0 = smB + srow * 32 + scol;
  for (int kk = 0; kk < 1024; kk += 32) {
    gl_lds16(Ab + kk, sA0);
    gl_lds16(Ab + kk + (size_t)64 * 1024, sA0 + 64 * 32);
    gl_lds16(Wb + kk, sB0);
    gl_lds16(Wb + kk + (size_t)64 * 1024, sB0 + 64 * 32);
    __syncthreads();
    bf16x8 af[4], bv[4];
#pragma unroll
    for (int i = 0; i < 4; i++) af[i] = *(const bf16x8*)(smA + (wr * 64 + i * 16 + l15) * 32 + lg * 8);
#pragma unroll
    for (int i = 0; i < 4; i++) bv[i] = *(const bf16x8*)(smB + (wc * 64 + i * 16 + l15) * 32 + lg * 8);
#pragma unroll
    for (int i = 0; i < 4; i++)
#pragma unroll
      for (int j = 0; j < 4; j++) acc[i][j] = MFMA16(af[i], bv[j], acc[i][j]);
    __syncthreads();
  }
#pragma unroll
  for (int j = 0; j < 4; j++) {
    const int n = n0 + wc * 64 + j * 16 + l15;
    const float bvj = bias[n];
#pragma unroll
    for (int i = 0; i < 4; i++) {
      const int mbase = m0 + wr * 64 + i * 16 + lg * 4;
      if (MODE == 0) {
        u16* o = (u16*)Out;
#pragma unroll
        for (int r = 0; r < 4; r++) {
          const int m = mbase + r;
          o[((size_t)((m >> 10) * 16 + (n >> 6)) << 16) + (size_t)(m & 1023) * 64 + (n & 63)] =
              f2bf(acc[i][j][r] + bvj);
        }
      } else if (MODE == 2) {
        u16* o = (u16*)Out;
        size_t off = ((size_t)((mbase >> 10) * 16 + (n >> 6)) << 16) + (size_t)(n & 63) * 1024 + (mbase & 1023);
        *(ushort4*)(o + off) = make_ushort4(f2bf(acc[i][j][0] + bvj), f2bf(acc[i][j][1] + bvj),
                                            f2bf(acc[i][j][2] + bvj), f2bf(acc[i][j][3] + bvj));
      } else {
        float* o = (float*)Out;
#pragma unroll
        for (int r = 0; r < 4; r++) o[(size_t)(mbase + r) * 1024 + n] = acc[i][j][r] + bvj;
      }
    }
  }
}

// ---------------- flash attention, swapped-QK^T, zero-LDS ----------------
// Wave owns 16 q-rows.  S^T[kv][q] from mfma(K,Q): lane q=l15, kv=nk*16+lg*4+r.
// P^T redistributed to PV B-frag via cvt_pk + permlane swaps.  O^T = V^T * P^T.
__global__ void __launch_bounds__(256) attn_kernel(const u16* __restrict__ Qp, const u16* __restrict__ Kp,
                                                   const u16* __restrict__ Vt, const u8* __restrict__ pack,
                                                   u16* __restrict__ ctx) {
  const int t = threadIdx.x;
  const int w = t >> 6, l = t & 63;
  const int l15 = l & 15, lg = l >> 4;
  const int bh = blockIdx.y;
  const int b = bh >> 4, h = bh & 15;
  const int q0 = blockIdx.x * 64 + w * 16;
  const u32 mbit = (h < 4) ? 1u : (h < 8) ? 2u : 0u;
  const u32 ebit = (h >= 8 && h < 10) ? 4u : (h >= 10 && h < 12) ? 8u : 0u;
  const size_t hb = (size_t)bh << 16;

  // Q fragment (B operand): col=q=l15, k-elems d = ks*32 + lg*8
  bf16x8 qf[2];
#pragma unroll
  for (int ks = 0; ks < 2; ks++)
    qf[ks] = *(const bf16x8*)(Qp + hb + (size_t)(q0 + l15) * 64 + ks * 32 + lg * 8);

  f32x4 octx[4] = {};
  float mrun = -3.0e38f, lrun = 0.0f;
  const u8* pkb = pack + (size_t)b * 1048576 + (size_t)(q0 + l15) * 1024 + lg * 4;

  for (int kb = 0; kb < 1024; kb += 64) {
    // QK^T (swapped): sc[nk][r] = S^T[kv=kb+nk*16+lg*4+r][q]
    f32x4 sc[4];
#pragma unroll
    for (int nk = 0; nk < 4; nk++) {
      const u16* kp = Kp + hb + (size_t)(kb + nk * 16 + l15) * 64 + lg * 8;
      bf16x8 kf0 = *(const bf16x8*)(kp);
      bf16x8 kf1 = *(const bf16x8*)(kp + 32);
      f32x4 z = {0.0f, 0.0f, 0.0f, 0.0f};
      z = MFMA16(kf0, qf[0], z);
      z = MFMA16(kf1, qf[1], z);
      sc[nk] = z;
    }
    // packed mask: byte r of pk[nk] is (q, kv=kb+nk*16+lg*4+r)
    u32 pk[4];
#pragma unroll
    for (int nk = 0; nk < 4; nk++) pk[nk] = *(const u32*)(pkb + kb + nk * 16);
    // mask + enhance + in-register row max
    float smax = -3.0e38f;
#pragma unroll
    for (int nk = 0; nk < 4; nk++)
#pragma unroll
      for (int r = 0; r < 4; r++) {
        float s = sc[nk][r] * 0.125f;
        u32 pb = (pk[nk] >> (r * 8)) & 0xffu;
        s += (pb & mbit) ? -1.0e9f : 0.0f;
        s += (pb & ebit) ? 5.0f * fabsf(s) : 0.0f;
        s = (pb & 16u) ? s : -1.0e9f;
        sc[nk][r] = s;
        smax = fmaxf(smax, s);
      }
    smax = redmax_lg(smax);
    const float mn = fmaxf(mrun, smax);
    const float so = __expf(mrun - mn);
    float psum = 0.0f;
#pragma unroll
    for (int nk = 0; nk < 4; nk++)
#pragma unroll
      for (int r = 0; r < 4; r++) {
        float p = __expf(sc[nk][r] - mn);
        sc[nk][r] = p;
        psum += p;
      }
    psum = redsum_lg(psum);
    lrun = lrun * so + psum;
    mrun = mn;
    // rescale accumulated context (scalar per lane: one q per lane)
#pragma unroll
    for (int nd = 0; nd < 4; nd++)
#pragma unroll
      for (int r = 0; r < 4; r++) octx[nd][r] *= so;
    // P^T -> PV B-fragments via cvt_pk + permlane swaps; PV: O^T += V^T * P^T
#pragma unroll
    for (int kk = 0; kk < 2; kk++) {
      u32 a0 = cvtpk(sc[2 * kk][0], sc[2 * kk][1]);
      u32 a1 = cvtpk(sc[2 * kk][2], sc[2 * kk][3]);
      u32 b0 = cvtpk(sc[2 * kk + 1][0], sc[2 * kk + 1][1]);
      u32 b1 = cvtpk(sc[2 * kk + 1][2], sc[2 * kk + 1][3]);
      plswap32(a0, b0);
      plswap32(a1, b1);
      plswap16(a0, b0);
      plswap16(a1, b1);
      u32x4 wv = {a0, a1, b0, b1};
      bf16x8 pfrag = __builtin_bit_cast(bf16x8, wv);
#pragma unroll
      for (int nd = 0; nd < 4; nd++) {
        bf16x8 vf = *(const bf16x8*)(Vt + hb + (size_t)(nd * 16 + l15) * 1024 + kb + kk * 32 + lg * 8);
        octx[nd] = MFMA16(vf, pfrag, octx[nd]);
      }
    }
  }
  // epilogue: lane has q=q0+l15, d = nd*16+lg*4+r ; store bf16 ctx[b][q][h*64+d]
  const float inv = 1.0f / lrun;
  u16* cb = ctx + (size_t)b * 1048576 + (size_t)(q0 + l15) * 1024 + h * 64 + lg * 4;
#pragma unroll
  for (int nd = 0; nd < 4; nd++) {
    *(ushort4*)(cb + nd * 16) = make_ushort4(f2bf(octx[nd][0] * inv), f2bf(octx[nd][1] * inv),
                                             f2bf(octx[nd][2] * inv), f2bf(octx[nd][3] * inv));
  }
}

extern "C" void kernel_launch(void* const* d_in, const int* in_sizes, int n_in,
                              void* d_out, int out_size, void* d_ws, size_t ws_size,
                              hipStream_t stream) {
  (void)in_sizes; (void)n_in; (void)out_size; (void)ws_size;
  const float* Q  = (const float*)d_in[0];
  const float* K  = (const float*)d_in[1];
  const float* V  = (const float*)d_in[2];
  const float* tok = (const float*)d_in[3];
  const float* st  = (const float*)d_in[4];
  const float* df  = (const float*)d_in[5];
  const float* cf  = (const float*)d_in[6];
  const int*   msk = (const int*)d_in[8];
  const float* Wq = (const float*)d_in[9];
  const float* bq = (const float*)d_in[10];
  const float* Wk = (const float*)d_in[11];
  const float* bk = (const float*)d_in[12];
  const float* Wv = (const float*)d_in[13];
  const float* bv = (const float*)d_in[14];
  const float* Wo = (const float*)d_in[15];
  const float* bo = (const float*)d_in[16];

  char* ws = (char*)d_ws;
  const size_t MB = 1ull << 20;
  u16* Qbf = (u16*)(ws);
  u16* Kbf = (u16*)(ws + 8 * MB);
  u16* Vbf = (u16*)(ws + 16 * MB);
  u16* Wqb = (u16*)(ws + 24 * MB);
  u16* Wkb = (u16*)(ws + 26 * MB);
  u16* Wvb = (u16*)(ws + 28 * MB);
  u16* Wob = (u16*)(ws + 30 * MB);
  u8*  pkQ = (u8*)(ws + 32 * MB);
  u16* Qh  = (u16*)(ws + 36 * MB);
  u16* Kh  = (u16*)(ws + 44 * MB);
  u16* VhT = (u16*)(ws + 52 * MB);
  u16* ctx = (u16*)(ws + 60 * MB);

  cvt3_kernel<<<4096, 256, 0, stream>>>((const float4*)Q, (const float4*)K, (const float4*)V,
                                        (ushort4*)Qbf, (ushort4*)Kbf, (ushort4*)Vbf, 1048576);
  cvt4_kernel<<<1024, 256, 0, stream>>>((const float4*)Wq, (const float4*)Wk, (const float4*)Wv, (const float4*)Wo,
                                        (ushort4*)Wqb, (ushort4*)Wkb, (ushort4*)Wvb, (ushort4*)Wob, 262144);
  pack_kernel<<<1024, 256, 0, stream>>>((const float4*)tok, (const float4*)st, (const float4*)df,
                                        (const float4*)cf, (const int4*)msk, (uint4*)pkQ);
  gemm_bt<0><<<dim3(8, 32), 256, 0, stream>>>(Qbf, Wqb, bq, Qh);
  gemm_bt<0><<<dim3(8, 32), 256, 0, stream>>>(Kbf, Wkb, bk, Kh);
  gemm_bt<2><<<dim3(8, 32), 256, 0, stream>>>(Vbf, Wvb, bv, VhT);
  attn_kernel<<<dim3(16, 64), 256, 0, stream>>>(Qh, Kh, VhT, pkQ, ctx);
  gemm_bt<3><<<dim3(8, 32), 256, 0, stream>>>(ctx, Wob, bo, (void*)d_out);
}

// Round 4
// 193.059 us; speedup vs baseline: 1.4705x; 1.4705x over previous
//
#include <hip/hip_runtime.h>
#include <stdint.h>

typedef unsigned short u16;
typedef unsigned int   u32;
typedef unsigned char  u8;
typedef __attribute__((ext_vector_type(4))) float f32x4;
typedef __attribute__((ext_vector_type(8))) __bf16 bf16x8;
typedef __attribute__((ext_vector_type(2))) unsigned int u32x2;
typedef __attribute__((ext_vector_type(4))) unsigned int u32x4;

#define MFMA16(a, b, c) __builtin_amdgcn_mfma_f32_16x16x32_bf16((a), (b), (c), 0, 0, 0)

__device__ __forceinline__ u16 f2bf(float f) {
  u32 u = __float_as_uint(f);
  return (u16)((u + 0x7fffu + ((u >> 16) & 1u)) >> 16);  // RNE
}

__device__ __forceinline__ void gl_lds16(const void* g, void* l) {
  __builtin_amdgcn_global_load_lds((const __attribute__((address_space(1))) u32*)g,
                                   (__attribute__((address_space(3))) u32*)l, 16, 0, 0);
}

// v_cvt_pk_bf16_f32: {lo=bf16(a), hi=bf16(b)} with RNE
__device__ __forceinline__ u32 cvtpk(float a, float b) {
  u32 r;
  asm("v_cvt_pk_bf16_f32 %0, %1, %2" : "=v"(r) : "v"(a), "v"(b));
  return r;
}

__device__ __forceinline__ void plswap32(u32& x, u32& y) {
  u32x2 r = __builtin_amdgcn_permlane32_swap(x, y, false, false);
  x = r.x; y = r.y;
}
__device__ __forceinline__ void plswap16(u32& x, u32& y) {
  u32x2 r = __builtin_amdgcn_permlane16_swap(x, y, false, false);
  x = r.x; y = r.y;
}

// reduce across the 4 lane-groups (lanes l15+16g); result in all lanes
__device__ __forceinline__ float redmax_lg(float v) {
  u32 x = __float_as_uint(v), y = x;
  plswap16(x, y);
  float m = fmaxf(__uint_as_float(x), __uint_as_float(y));
  u32 a = __float_as_uint(m), b = a;
  plswap32(a, b);
  return fmaxf(__uint_as_float(a), __uint_as_float(b));
}
__device__ __forceinline__ float redsum_lg(float v) {
  u32 x = __float_as_uint(v), y = x;
  plswap16(x, y);
  float m = __uint_as_float(x) + __uint_as_float(y);
  u32 a = __float_as_uint(m), b = a;
  plswap32(a, b);
  return __uint_as_float(a) + __uint_as_float(b);
}

// ---------------- f32 -> bf16 converters ----------------
__global__ void __launch_bounds__(256) cvt3_kernel(const float4* __restrict__ a, const float4* __restrict__ b,
                                                   const float4* __restrict__ c, ushort4* __restrict__ oa,
                                                   ushort4* __restrict__ ob, ushort4* __restrict__ oc, int n4) {
  int i = blockIdx.x * 256 + threadIdx.x;
  if (i >= n4) return;
  float4 v;
  v = a[i]; oa[i] = make_ushort4(f2bf(v.x), f2bf(v.y), f2bf(v.z), f2bf(v.w));
  v = b[i]; ob[i] = make_ushort4(f2bf(v.x), f2bf(v.y), f2bf(v.z), f2bf(v.w));
  v = c[i]; oc[i] = make_ushort4(f2bf(v.x), f2bf(v.y), f2bf(v.z), f2bf(v.w));
}

__global__ void __launch_bounds__(256) cvt4_kernel(const float4* __restrict__ a, const float4* __restrict__ b,
                                                   const float4* __restrict__ c, const float4* __restrict__ d,
                                                   ushort4* __restrict__ oa, ushort4* __restrict__ ob,
                                                   ushort4* __restrict__ oc, ushort4* __restrict__ od, int n4) {
  int i = blockIdx.x * 256 + threadIdx.x;
  if (i >= n4) return;
  float4 v;
  v = a[i]; oa[i] = make_ushort4(f2bf(v.x), f2bf(v.y), f2bf(v.z), f2bf(v.w));
  v = b[i]; ob[i] = make_ushort4(f2bf(v.x), f2bf(v.y), f2bf(v.z), f2bf(v.w));
  v = c[i]; oc[i] = make_ushort4(f2bf(v.x), f2bf(v.y), f2bf(v.z), f2bf(v.w));
  v = d[i]; od[i] = make_ushort4(f2bf(v.x), f2bf(v.y), f2bf(v.z), f2bf(v.w));
}

// ---------------- pack 5 boolean matrices into a wave-tiled byte layout ----------------
// u32 index = ((b*64 + q/16)*16 + t)*256 + (q&15)*16 + lg*4 + nk
// holds bits for (q, kv = t*64 + nk*16 + lg*4 + r) in byte r.
__device__ __forceinline__ u32 pbit(float t, float s, float d, float c, int m) {
  return (t != 0.0f ? 1u : 0u) | (s != 0.0f ? 2u : 0u) | (d != 0.0f ? 4u : 0u) |
         (c != 0.0f ? 8u : 0u) | (m != 0 ? 16u : 0u);
}

__global__ void __launch_bounds__(256) pack_kernel(const float4* __restrict__ tok, const float4* __restrict__ st,
                                                   const float4* __restrict__ df, const float4* __restrict__ cf,
                                                   const int4* __restrict__ msk, u32* __restrict__ out) {
  int i = blockIdx.x * 256 + threadIdx.x;  // 16 input elements per thread
  if (i >= 262144) return;
  const int b = i >> 16, rem = i & 65535, q = rem >> 6, kc = rem & 63;
  const u32 base = ((u32)(b * 64 + (q >> 4)) * 16 + (kc >> 2)) * 256 + (q & 15) * 16 + (kc & 3);
#pragma unroll
  for (int j = 0; j < 4; j++) {
    float4 vt = tok[i * 4 + j], vs = st[i * 4 + j], vd = df[i * 4 + j], vc = cf[i * 4 + j];
    int4 vm = msk[i * 4 + j];
    u32 b0 = pbit(vt.x, vs.x, vd.x, vc.x, vm.x);
    u32 b1 = pbit(vt.y, vs.y, vd.y, vc.y, vm.y);
    u32 b2 = pbit(vt.z, vs.z, vd.z, vc.z, vm.z);
    u32 b3 = pbit(vt.w, vs.w, vd.w, vc.w, vm.w);
    out[base + j * 4] = b0 | (b1 << 8) | (b2 << 16) | (b3 << 24);
  }
}

// ---------------- bf16 GEMM: C[m][n] = sum_k A[m][k]*W[n][k] + bias[n] ----------------
template <int MODE>
__global__ void __launch_bounds__(256) gemm_bt(const u16* __restrict__ A, const u16* __restrict__ W,
                                               const float* __restrict__ bias, void* __restrict__ Out) {
  __shared__ u16 smA[128 * 32];
  __shared__ u16 smB[128 * 32];
  const int t = threadIdx.x;
  const int w = t >> 6, l = t & 63;
  const int l15 = l & 15, lg = l >> 4;
  const int m0 = blockIdx.y * 128, n0 = blockIdx.x * 128;
  const int wr = w >> 1, wc = w & 1;
  f32x4 acc[4][4] = {};
  const int srow = w * 16 + (l >> 2);
  const int scol = (l & 3) * 8;
  const u16* Ab = A + (size_t)(m0 + srow) * 1024 + scol;
  const u16* Wb = W + (size_t)(n0 + srow) * 1024 + scol;
  u16* sA0 = smA + srow * 32 + scol;
  u16* sB0 = smB + srow * 32 + scol;
  for (int kk = 0; kk < 1024; kk += 32) {
    gl_lds16(Ab + kk, sA0);
    gl_lds16(Ab + kk + (size_t)64 * 1024, sA0 + 64 * 32);
    gl_lds16(Wb + kk, sB0);
    gl_lds16(Wb + kk + (size_t)64 * 1024, sB0 + 64 * 32);
    __syncthreads();
    bf16x8 af[4], bv[4];
#pragma unroll
    for (int i = 0; i < 4; i++) af[i] = *(const bf16x8*)(smA + (wr * 64 + i * 16 + l15) * 32 + lg * 8);
#pragma unroll
    for (int i = 0; i < 4; i++) bv[i] = *(const bf16x8*)(smB + (wc * 64 + i * 16 + l15) * 32 + lg * 8);
#pragma unroll
    for (int i = 0; i < 4; i++)
#pragma unroll
      for (int j = 0; j < 4; j++) acc[i][j] = MFMA16(af[i], bv[j], acc[i][j]);
    __syncthreads();
  }
#pragma unroll
  for (int j = 0; j < 4; j++) {
    const int n = n0 + wc * 64 + j * 16 + l15;
    const float bvj = bias[n];
#pragma unroll
    for (int i = 0; i < 4; i++) {
      const int mbase = m0 + wr * 64 + i * 16 + lg * 4;
      if (MODE == 0) {
        u16* o = (u16*)Out;
#pragma unroll
        for (int r = 0; r < 4; r++) {
          const int m = mbase + r;
          o[((size_t)((m >> 10) * 16 + (n >> 6)) << 16) + (size_t)(m & 1023) * 64 + (n & 63)] =
              f2bf(acc[i][j][r] + bvj);
        }
      } else if (MODE == 2) {
        u16* o = (u16*)Out;
        size_t off = ((size_t)((mbase >> 10) * 16 + (n >> 6)) << 16) + (size_t)(n & 63) * 1024 + (mbase & 1023);
        *(ushort4*)(o + off) = make_ushort4(f2bf(acc[i][j][0] + bvj), f2bf(acc[i][j][1] + bvj),
                                            f2bf(acc[i][j][2] + bvj), f2bf(acc[i][j][3] + bvj));
      } else {
        float* o = (float*)Out;
#pragma unroll
        for (int r = 0; r < 4; r++) o[(size_t)(mbase + r) * 1024 + n] = acc[i][j][r] + bvj;
      }
    }
  }
}

// ---------------- flash attention: LDS-staged K/V (double-buffered), swapped-QK^T ----------------
__global__ void __launch_bounds__(256) attn_kernel(const u16* __restrict__ Qp, const u16* __restrict__ Kp,
                                                   const u16* __restrict__ Vt, const u8* __restrict__ pack,
                                                   u16* __restrict__ ctx) {
  __shared__ u16 smK[2][4096];
  __shared__ u16 smV[2][4096];
  const int tid = threadIdx.x;
  const int w = tid >> 6, l = tid & 63;
  const int l15 = l & 15, lg = l >> 4;
  // bijective XCD swizzle: all 16 q-blocks of one bh land on one XCD
  const int f = blockIdx.x;
  const int swz = (f & 7) * 128 + (f >> 3);
  const int bh = swz >> 4, bx = swz & 15;
  const int b = bh >> 4, h = bh & 15;
  const int q0 = bx * 64 + w * 16;
  const u32 mbit = (h < 4) ? 1u : (h < 8) ? 2u : 0u;
  const u32 ebit = (h >= 8 && h < 10) ? 4u : (h >= 10 && h < 12) ? 8u : 0u;
  const size_t hb = (size_t)bh << 16;

  // Q fragment (B operand): col=q=l15, k-elems d = ks*32 + lg*8
  bf16x8 qf[2];
#pragma unroll
  for (int ks = 0; ks < 2; ks++)
    qf[ks] = *(const bf16x8*)(Qp + hb + (size_t)(q0 + l15) * 64 + ks * 32 + lg * 8);

  // staging lane constants (two gl_lds per tile per wave; rows srow and srow+8)
  const int srow = w * 16 + (l >> 3);
  const int schunk = (l & 7) ^ (l >> 3);  // logical 8-elem chunk for physical slot l&7
  const u16* Ksrc = Kp + hb + (size_t)srow * 64 + schunk * 8;
  const u16* Vsrc = Vt + hb + (size_t)srow * 1024 + schunk * 8;
  // LDS read constant: physical chunk offset (u16 units) for logical chunk lg
  const int c0 = (lg ^ (l15 & 7)) * 8;

  // pack: one coalesced dwordx4 per wave per step
  const u8* pkq = pack + ((size_t)((b * 64 + bx * 4 + w) * 16)) * 1024 + (l15 * 4 + lg) * 16;

  // prologue: stage t=0 into buffer 0, prefetch pack(0)
  gl_lds16(Ksrc, &smK[0][w * 1024]);
  gl_lds16(Ksrc + 512, &smK[0][w * 1024 + 512]);
  gl_lds16(Vsrc, &smV[0][w * 1024]);
  gl_lds16(Vsrc + 8192, &smV[0][w * 1024 + 512]);
  uint4 pk_next = *(const uint4*)(pkq);

  f32x4 octx[4] = {};
  float mrun = -3.0e38f, lrun = 0.0f;

  for (int t = 0; t < 16; t++) {
    __syncthreads();  // implicit vmcnt(0): stage(t) drained; all waves done with buf[(t+1)&1]
    const uint4 pkc = pk_next;
    if (t < 15) {
      const int kb = (t + 1) * 64;
      const int nb = (t + 1) & 1;
      gl_lds16(Ksrc + (size_t)kb * 64, &smK[nb][w * 1024]);
      gl_lds16(Ksrc + (size_t)kb * 64 + 512, &smK[nb][w * 1024 + 512]);
      gl_lds16(Vsrc + kb, &smV[nb][w * 1024]);
      gl_lds16(Vsrc + kb + 8192, &smV[nb][w * 1024 + 512]);
      pk_next = *(const uint4*)(pkq + (t + 1) * 1024);
    }
    const u16* bK = smK[t & 1];
    const u16* bV = smV[t & 1];
    // QK^T (swapped): sc[nk][r] = S^T[kv = t*64 + nk*16 + lg*4 + r][q = l15]
    f32x4 sc[4];
#pragma unroll
    for (int nk = 0; nk < 4; nk++) {
      const u16* kr = bK + (nk * 16 + l15) * 64;
      bf16x8 kf0 = *(const bf16x8*)(kr + c0);
      bf16x8 kf1 = *(const bf16x8*)(kr + (c0 ^ 32));
      f32x4 z = {0.0f, 0.0f, 0.0f, 0.0f};
      z = MFMA16(kf0, qf[0], z);
      z = MFMA16(kf1, qf[1], z);
      sc[nk] = z;
    }
    const u32 pkw[4] = {pkc.x, pkc.y, pkc.z, pkc.w};
    // mask + enhance + in-register row max
    float smax = -3.0e38f;
#pragma unroll
    for (int nk = 0; nk < 4; nk++)
#pragma unroll
      for (int r = 0; r < 4; r++) {
        float s = sc[nk][r] * 0.125f;
        u32 pb = (pkw[nk] >> (r * 8)) & 0xffu;
        s += (pb & mbit) ? -1.0e9f : 0.0f;
        s += (pb & ebit) ? 5.0f * fabsf(s) : 0.0f;
        s = (pb & 16u) ? s : -1.0e9f;
        sc[nk][r] = s;
        smax = fmaxf(smax, s);
      }
    smax = redmax_lg(smax);
    const float mn = fmaxf(mrun, smax);
    const float so = __expf(mrun - mn);
    float psum = 0.0f;
#pragma unroll
    for (int nk = 0; nk < 4; nk++)
#pragma unroll
      for (int r = 0; r < 4; r++) {
        float p = __expf(sc[nk][r] - mn);
        sc[nk][r] = p;
        psum += p;
      }
    psum = redsum_lg(psum);
    lrun = lrun * so + psum;
    mrun = mn;
#pragma unroll
    for (int nd = 0; nd < 4; nd++)
#pragma unroll
      for (int r = 0; r < 4; r++) octx[nd][r] *= so;
    // P^T -> PV B-fragments via cvt_pk + permlane swaps; PV: O^T += V^T * P^T
#pragma unroll
    for (int kk = 0; kk < 2; kk++) {
      u32 a0 = cvtpk(sc[2 * kk][0], sc[2 * kk][1]);
      u32 a1 = cvtpk(sc[2 * kk][2], sc[2 * kk][3]);
      u32 b0 = cvtpk(sc[2 * kk + 1][0], sc[2 * kk + 1][1]);
      u32 b1 = cvtpk(sc[2 * kk + 1][2], sc[2 * kk + 1][3]);
      plswap32(a0, b0);
      plswap32(a1, b1);
      plswap16(a0, b0);
      plswap16(a1, b1);
      u32x4 wv = {a0, a1, b0, b1};
      bf16x8 pfrag = __builtin_bit_cast(bf16x8, wv);
#pragma unroll
      for (int nd = 0; nd < 4; nd++) {
        bf16x8 vf = *(const bf16x8*)(bV + (nd * 16 + l15) * 64 + (c0 ^ (kk * 32)));
        octx[nd] = MFMA16(vf, pfrag, octx[nd]);
      }
    }
  }
  // epilogue: lane has q=q0+l15, d = nd*16+lg*4+r ; store bf16 ctx[b][q][h*64+d]
  const float inv = 1.0f / lrun;
  u16* cb = ctx + (size_t)b * 1048576 + (size_t)(q0 + l15) * 1024 + h * 64 + lg * 4;
#pragma unroll
  for (int nd = 0; nd < 4; nd++) {
    *(ushort4*)(cb + nd * 16) = make_ushort4(f2bf(octx[nd][0] * inv), f2bf(octx[nd][1] * inv),
                                             f2bf(octx[nd][2] * inv), f2bf(octx[nd][3] * inv));
  }
}

extern "C" void kernel_launch(void* const* d_in, const int* in_sizes, int n_in,
                              void* d_out, int out_size, void* d_ws, size_t ws_size,
                              hipStream_t stream) {
  (void)in_sizes; (void)n_in; (void)out_size; (void)ws_size;
  const float* Q  = (const float*)d_in[0];
  const float* K  = (const float*)d_in[1];
  const float* V  = (const float*)d_in[2];
  const float* tok = (const float*)d_in[3];
  const float* st  = (const float*)d_in[4];
  const float* df  = (const float*)d_in[5];
  const float* cf  = (const float*)d_in[6];
  const int*   msk = (const int*)d_in[8];
  const float* Wq = (const float*)d_in[9];
  const float* bq = (const float*)d_in[10];
  const float* Wk = (const float*)d_in[11];
  const float* bk = (const float*)d_in[12];
  const float* Wv = (const float*)d_in[13];
  const float* bv = (const float*)d_in[14];
  const float* Wo = (const float*)d_in[15];
  const float* bo = (const float*)d_in[16];

  char* ws = (char*)d_ws;
  const size_t MB = 1ull << 20;
  u16* Qbf = (u16*)(ws);
  u16* Kbf = (u16*)(ws + 8 * MB);
  u16* Vbf = (u16*)(ws + 16 * MB);
  u16* Wqb = (u16*)(ws + 24 * MB);
  u16* Wkb = (u16*)(ws + 26 * MB);
  u16* Wvb = (u16*)(ws + 28 * MB);
  u16* Wob = (u16*)(ws + 30 * MB);
  u8*  pkQ = (u8*)(ws + 32 * MB);
  u16* Qh  = (u16*)(ws + 36 * MB);
  u16* Kh  = (u16*)(ws + 44 * MB);
  u16* VhT = (u16*)(ws + 52 * MB);
  u16* ctx = (u16*)(ws + 60 * MB);

  cvt3_kernel<<<4096, 256, 0, stream>>>((const float4*)Q, (const float4*)K, (const float4*)V,
                                        (ushort4*)Qbf, (ushort4*)Kbf, (ushort4*)Vbf, 1048576);
  cvt4_kernel<<<1024, 256, 0, stream>>>((const float4*)Wq, (const float4*)Wk, (const float4*)Wv, (const float4*)Wo,
                                        (ushort4*)Wqb, (ushort4*)Wkb, (ushort4*)Wvb, (ushort4*)Wob, 262144);
  pack_kernel<<<1024, 256, 0, stream>>>((const float4*)tok, (const float4*)st, (const float4*)df,
                                        (const float4*)cf, (const int4*)msk, (u32*)pkQ);
  gemm_bt<0><<<dim3(8, 32), 256, 0, stream>>>(Qbf, Wqb, bq, Qh);
  gemm_bt<0><<<dim3(8, 32), 256, 0, stream>>>(Kbf, Wkb, bk, Kh);
  gemm_bt<2><<<dim3(8, 32), 256, 0, stream>>>(Vbf, Wvb, bv, VhT);
  attn_kernel<<<1024, 256, 0, stream>>>(Qh, Kh, VhT, pkQ, ctx);
  gemm_bt<3><<<dim3(8, 32), 256, 0, stream>>>(ctx, Wob, bo, (void*)d_out);
}

// Round 5
// 161.804 us; speedup vs baseline: 1.7545x; 1.1932x over previous
//
#include <hip/hip_runtime.h>
#include <stdint.h>

typedef unsigned short u16;
typedef unsigned int   u32;
typedef unsigned char  u8;
typedef __attribute__((ext_vector_type(4))) float f32x4;
typedef __attribute__((ext_vector_type(8))) __bf16 bf16x8;
typedef __attribute__((ext_vector_type(2))) unsigned int u32x2;
typedef __attribute__((ext_vector_type(4))) unsigned int u32x4;

#define MFMA16(a, b, c) __builtin_amdgcn_mfma_f32_16x16x32_bf16((a), (b), (c), 0, 0, 0)

__device__ __forceinline__ u16 f2bf(float f) {
  u32 u = __float_as_uint(f);
  return (u16)((u + 0x7fffu + ((u >> 16) & 1u)) >> 16);  // RNE
}

__device__ __forceinline__ void gl_lds16(const void* g, void* l) {
  __builtin_amdgcn_global_load_lds((const __attribute__((address_space(1))) u32*)g,
                                   (__attribute__((address_space(3))) u32*)l, 16, 0, 0);
}

__device__ __forceinline__ u32 cvtpk(float a, float b) {
  u32 r;
  asm("v_cvt_pk_bf16_f32 %0, %1, %2" : "=v"(r) : "v"(a), "v"(b));
  return r;
}

__device__ __forceinline__ float exp2_hw(float x) {  // v_exp_f32 = 2^x
  float r;
  asm("v_exp_f32 %0, %1" : "=v"(r) : "v"(x));
  return r;
}

__device__ __forceinline__ void plswap32(u32& x, u32& y) {
  u32x2 r = __builtin_amdgcn_permlane32_swap(x, y, false, false);
  x = r.x; y = r.y;
}
__device__ __forceinline__ void plswap16(u32& x, u32& y) {
  u32x2 r = __builtin_amdgcn_permlane16_swap(x, y, false, false);
  x = r.x; y = r.y;
}

__device__ __forceinline__ float redmax_lg(float v) {
  u32 x = __float_as_uint(v), y = x;
  plswap16(x, y);
  float m = fmaxf(__uint_as_float(x), __uint_as_float(y));
  u32 a = __float_as_uint(m), b = a;
  plswap32(a, b);
  return fmaxf(__uint_as_float(a), __uint_as_float(b));
}
__device__ __forceinline__ float redsum_lg(float v) {
  u32 x = __float_as_uint(v), y = x;
  plswap16(x, y);
  float m = __uint_as_float(x) + __uint_as_float(y);
  u32 a = __float_as_uint(m), b = a;
  plswap32(a, b);
  return __uint_as_float(a) + __uint_as_float(b);
}

// ---------------- f32 -> bf16 converter (QKV + all weights, one kernel) ----------------
__global__ void __launch_bounds__(256) cvt_all(const float4* __restrict__ Q, const float4* __restrict__ K,
                                               const float4* __restrict__ V, const float4* __restrict__ Wq,
                                               const float4* __restrict__ Wk, const float4* __restrict__ Wv,
                                               const float4* __restrict__ Wo, ushort4* __restrict__ oQ,
                                               ushort4* __restrict__ oK, ushort4* __restrict__ oV,
                                               ushort4* __restrict__ oWq, ushort4* __restrict__ oWk,
                                               ushort4* __restrict__ oWv, ushort4* __restrict__ oWo) {
  const int i = blockIdx.x * 256 + threadIdx.x;
  float4 v;
  if (blockIdx.x < 4096) {  // 1048576 float4 per QKV stream
    v = Q[i]; oQ[i] = make_ushort4(f2bf(v.x), f2bf(v.y), f2bf(v.z), f2bf(v.w));
    v = K[i]; oK[i] = make_ushort4(f2bf(v.x), f2bf(v.y), f2bf(v.z), f2bf(v.w));
    v = V[i]; oV[i] = make_ushort4(f2bf(v.x), f2bf(v.y), f2bf(v.z), f2bf(v.w));
  } else {  // 262144 float4 per weight stream
    const int j = i - 4096 * 256;
    v = Wq[j]; oWq[j] = make_ushort4(f2bf(v.x), f2bf(v.y), f2bf(v.z), f2bf(v.w));
    v = Wk[j]; oWk[j] = make_ushort4(f2bf(v.x), f2bf(v.y), f2bf(v.z), f2bf(v.w));
    v = Wv[j]; oWv[j] = make_ushort4(f2bf(v.x), f2bf(v.y), f2bf(v.z), f2bf(v.w));
    v = Wo[j]; oWo[j] = make_ushort4(f2bf(v.x), f2bf(v.y), f2bf(v.z), f2bf(v.w));
  }
}

// ---------------- pack 5 boolean matrices + precombined kill bits ----------------
// u32 index = ((b*64 + q/16)*16 + t)*256 + (q&15)*16 + lg*4 + nk ; byte r = (q, kv=t*64+nk*16+lg*4+r)
// bits: 0=token 1=stmt 2=df 3=cf 4=mask!=0 5=token|!mask 6=stmt|!mask 7=!mask
__device__ __forceinline__ u32 pbit(float t, float s, float d, float c, int m) {
  const u32 nm = (m == 0) ? 1u : 0u;
  u32 r = (t != 0.0f ? 1u : 0u) | (s != 0.0f ? 2u : 0u) | (d != 0.0f ? 4u : 0u) |
          (c != 0.0f ? 8u : 0u) | ((1u - nm) << 4);
  r |= (((t != 0.0f ? 1u : 0u) | nm) << 5) | (((s != 0.0f ? 1u : 0u) | nm) << 6) | (nm << 7);
  return r;
}

__global__ void __launch_bounds__(256) pack_kernel(const float4* __restrict__ tok, const float4* __restrict__ st,
                                                   const float4* __restrict__ df, const float4* __restrict__ cf,
                                                   const int4* __restrict__ msk, u32* __restrict__ out) {
  int i = blockIdx.x * 256 + threadIdx.x;  // 16 input elements per thread
  if (i >= 262144) return;
  const int b = i >> 16, rem = i & 65535, q = rem >> 6, kc = rem & 63;
  const u32 base = ((u32)(b * 64 + (q >> 4)) * 16 + (kc >> 2)) * 256 + (q & 15) * 16 + (kc & 3);
#pragma unroll
  for (int j = 0; j < 4; j++) {
    float4 vt = tok[i * 4 + j], vs = st[i * 4 + j], vd = df[i * 4 + j], vc = cf[i * 4 + j];
    int4 vm = msk[i * 4 + j];
    u32 b0 = pbit(vt.x, vs.x, vd.x, vc.x, vm.x);
    u32 b1 = pbit(vt.y, vs.y, vd.y, vc.y, vm.y);
    u32 b2 = pbit(vt.z, vs.z, vd.z, vc.z, vm.z);
    u32 b3 = pbit(vt.w, vs.w, vd.w, vc.w, vm.w);
    out[base + j * 4] = b0 | (b1 << 8) | (b2 << 16) | (b3 << 24);
  }
}

// ---------------- batched QKV projection GEMM: z selects {Q,K,V} ----------------
// z<2: write bf16 head-major  out[(b*16+h)*65536 + s*64 + d]
// z=2: write bf16 transposed  out[(b*16+h)*65536 + d*1024 + s]
__global__ void __launch_bounds__(256) gemm_qkv(const u16* __restrict__ Abase, const u16* __restrict__ Wbase,
                                                const float* __restrict__ bq, const float* __restrict__ bk,
                                                const float* __restrict__ bv, u16* __restrict__ Obase) {
  __shared__ u16 smA[128 * 32];
  __shared__ u16 smB[128 * 32];
  const int z = blockIdx.z;
  const u16* A = Abase + (size_t)z * 4194304;
  const u16* W = Wbase + (size_t)z * 1048576;
  const float* bias = (z == 0) ? bq : (z == 1) ? bk : bv;
  u16* Out = Obase + (size_t)z * 4194304;
  const int t = threadIdx.x;
  const int w = t >> 6, l = t & 63;
  const int l15 = l & 15, lg = l >> 4;
  const int m0 = blockIdx.y * 128, n0 = blockIdx.x * 128;
  const int wr = w >> 1, wc = w & 1;
  f32x4 acc[4][4] = {};
  const int srow = w * 16 + (l >> 2);
  const int scol = (l & 3) * 8;
  const u16* Ab = A + (size_t)(m0 + srow) * 1024 + scol;
  const u16* Wb = W + (size_t)(n0 + srow) * 1024 + scol;
  u16* sA0 = smA + srow * 32 + scol;
  u16* sB0 = smB + srow * 32 + scol;
  for (int kk = 0; kk < 1024; kk += 32) {
    gl_lds16(Ab + kk, sA0);
    gl_lds16(Ab + kk + (size_t)64 * 1024, sA0 + 64 * 32);
    gl_lds16(Wb + kk, sB0);
    gl_lds16(Wb + kk + (size_t)64 * 1024, sB0 + 64 * 32);
    __syncthreads();
    bf16x8 af[4], bv_[4];
#pragma unroll
    for (int i = 0; i < 4; i++) af[i] = *(const bf16x8*)(smA + (wr * 64 + i * 16 + l15) * 32 + lg * 8);
#pragma unroll
    for (int i = 0; i < 4; i++) bv_[i] = *(const bf16x8*)(smB + (wc * 64 + i * 16 + l15) * 32 + lg * 8);
#pragma unroll
    for (int i = 0; i < 4; i++)
#pragma unroll
      for (int j = 0; j < 4; j++) acc[i][j] = MFMA16(af[i], bv_[j], acc[i][j]);
    __syncthreads();
  }
#pragma unroll
  for (int j = 0; j < 4; j++) {
    const int n = n0 + wc * 64 + j * 16 + l15;
    const float bvj = bias[n];
#pragma unroll
    for (int i = 0; i < 4; i++) {
      const int mbase = m0 + wr * 64 + i * 16 + lg * 4;
      if (z < 2) {
#pragma unroll
        for (int r = 0; r < 4; r++) {
          const int m = mbase + r;
          Out[((size_t)((m >> 10) * 16 + (n >> 6)) << 16) + (size_t)(m & 1023) * 64 + (n & 63)] =
              f2bf(acc[i][j][r] + bvj);
        }
      } else {
        size_t off = ((size_t)((mbase >> 10) * 16 + (n >> 6)) << 16) + (size_t)(n & 63) * 1024 + (mbase & 1023);
        *(ushort4*)(Out + off) = make_ushort4(f2bf(acc[i][j][0] + bvj), f2bf(acc[i][j][1] + bvj),
                                              f2bf(acc[i][j][2] + bvj), f2bf(acc[i][j][3] + bvj));
      }
    }
  }
}

// ---------------- output projection GEMM (f32 out) ----------------
__global__ void __launch_bounds__(256) gemm_out(const u16* __restrict__ A, const u16* __restrict__ W,
                                                const float* __restrict__ bias, float* __restrict__ Out) {
  __shared__ u16 smA[128 * 32];
  __shared__ u16 smB[128 * 32];
  const int t = threadIdx.x;
  const int w = t >> 6, l = t & 63;
  const int l15 = l & 15, lg = l >> 4;
  const int m0 = blockIdx.y * 128, n0 = blockIdx.x * 128;
  const int wr = w >> 1, wc = w & 1;
  f32x4 acc[4][4] = {};
  const int srow = w * 16 + (l >> 2);
  const int scol = (l & 3) * 8;
  const u16* Ab = A + (size_t)(m0 + srow) * 1024 + scol;
  const u16* Wb = W + (size_t)(n0 + srow) * 1024 + scol;
  u16* sA0 = smA + srow * 32 + scol;
  u16* sB0 = smB + srow * 32 + scol;
  for (int kk = 0; kk < 1024; kk += 32) {
    gl_lds16(Ab + kk, sA0);
    gl_lds16(Ab + kk + (size_t)64 * 1024, sA0 + 64 * 32);
    gl_lds16(Wb + kk, sB0);
    gl_lds16(Wb + kk + (size_t)64 * 1024, sB0 + 64 * 32);
    __syncthreads();
    bf16x8 af[4], bv_[4];
#pragma unroll
    for (int i = 0; i < 4; i++) af[i] = *(const bf16x8*)(smA + (wr * 64 + i * 16 + l15) * 32 + lg * 8);
#pragma unroll
    for (int i = 0; i < 4; i++) bv_[i] = *(const bf16x8*)(smB + (wc * 64 + i * 16 + l15) * 32 + lg * 8);
#pragma unroll
    for (int i = 0; i < 4; i++)
#pragma unroll
      for (int j = 0; j < 4; j++) acc[i][j] = MFMA16(af[i], bv_[j], acc[i][j]);
    __syncthreads();
  }
#pragma unroll
  for (int j = 0; j < 4; j++) {
    const int n = n0 + wc * 64 + j * 16 + l15;
    const float bvj = bias[n];
#pragma unroll
    for (int i = 0; i < 4; i++) {
      const int mbase = m0 + wr * 64 + i * 16 + lg * 4;
#pragma unroll
      for (int r = 0; r < 4; r++) Out[(size_t)(mbase + r) * 1024 + n] = acc[i][j][r] + bvj;
    }
  }
}

// ---------------- flash attention: LDS-staged K/V, log2-domain softmax, T13 defer ----------------
__global__ void __launch_bounds__(256) attn_kernel(const u16* __restrict__ Qp, const u16* __restrict__ Kp,
                                                   const u16* __restrict__ Vt, const u8* __restrict__ pack,
                                                   u16* __restrict__ ctx) {
  __shared__ u16 smK[2][4096];
  __shared__ u16 smV[2][4096];
  const float SCL  = 0.18033688011112042f;  // 0.125 * log2(e)
  const float NEGL = -1.44269504e9f;        // -1e9 * log2(e)
  const int tid = threadIdx.x;
  const int w = tid >> 6, l = tid & 63;
  const int l15 = l & 15, lg = l >> 4;
  const int f = blockIdx.x;
  const int swz = (f & 7) * 128 + (f >> 3);  // bijective XCD swizzle
  const int bh = swz >> 4, bx = swz & 15;
  const int b = bh >> 4, h = bh & 15;
  const int q0 = bx * 64 + w * 16;
  // head class: 0..7 kill-heads (bit5/bit6 precombined with !mask), 8..11 enhance, 12..15 std
  const bool enh = (h >= 8 && h < 12);
  const u32 kbit = (h < 4) ? 0x20u : (h < 8) ? 0x40u : 0x80u;
  const u32 ebit = (h < 10) ? 0x04u : 0x08u;  // only used when enh
  const u32 kb_[4] = {kbit, kbit << 8, kbit << 16, kbit << 24};
  const u32 eb_[4] = {ebit, ebit << 8, ebit << 16, ebit << 24};
  const size_t hb = (size_t)bh << 16;

  bf16x8 qf[2];
#pragma unroll
  for (int ks = 0; ks < 2; ks++)
    qf[ks] = *(const bf16x8*)(Qp + hb + (size_t)(q0 + l15) * 64 + ks * 32 + lg * 8);

  const int srow = w * 16 + (l >> 3);
  const int schunk = (l & 7) ^ (l >> 3);
  const u16* Ksrc = Kp + hb + (size_t)srow * 64 + schunk * 8;
  const u16* Vsrc = Vt + hb + (size_t)srow * 1024 + schunk * 8;
  const int c0 = (lg ^ (l15 & 7)) * 8;
  const u8* pkq = pack + ((size_t)((b * 64 + bx * 4 + w) * 16)) * 1024 + (l15 * 4 + lg) * 16;

  gl_lds16(Ksrc, &smK[0][w * 1024]);
  gl_lds16(Ksrc + 512, &smK[0][w * 1024 + 512]);
  gl_lds16(Vsrc, &smV[0][w * 1024]);
  gl_lds16(Vsrc + 8192, &smV[0][w * 1024 + 512]);
  uint4 pk_next = *(const uint4*)(pkq);

  f32x4 octx[4] = {};
  float mrun = -3.0e38f, lrun = 0.0f;

  for (int t = 0; t < 16; t++) {
    __syncthreads();
    const uint4 pkc = pk_next;
    if (t < 15) {
      const int kb = (t + 1) * 64;
      const int nb = (t + 1) & 1;
      gl_lds16(Ksrc + (size_t)kb * 64, &smK[nb][w * 1024]);
      gl_lds16(Ksrc + (size_t)kb * 64 + 512, &smK[nb][w * 1024 + 512]);
      gl_lds16(Vsrc + kb, &smV[nb][w * 1024]);
      gl_lds16(Vsrc + kb + 8192, &smV[nb][w * 1024 + 512]);
      pk_next = *(const uint4*)(pkq + (t + 1) * 1024);
    }
    const u16* bK = smK[t & 1];
    const u16* bV = smV[t & 1];
    f32x4 sc[4];
#pragma unroll
    for (int nk = 0; nk < 4; nk++) {
      const u16* kr = bK + (nk * 16 + l15) * 64;
      bf16x8 kf0 = *(const bf16x8*)(kr + c0);
      bf16x8 kf1 = *(const bf16x8*)(kr + (c0 ^ 32));
      f32x4 z = {0.0f, 0.0f, 0.0f, 0.0f};
      z = MFMA16(kf0, qf[0], z);
      z = MFMA16(kf1, qf[1], z);
      sc[nk] = z;
    }
    const u32 pkw[4] = {pkc.x, pkc.y, pkc.z, pkc.w};
    // scale -> (enhance) -> kill, per head class; all in log2 domain
#pragma unroll
    for (int nk = 0; nk < 4; nk++)
#pragma unroll
      for (int r = 0; r < 4; r++) {
        float s = sc[nk][r] * SCL;
        if (enh) s = (pkw[nk] & eb_[r]) ? __builtin_fmaf(fabsf(s), 5.0f, s) : s;
        sc[nk][r] = (pkw[nk] & kb_[r]) ? NEGL : s;
      }
    // row max (tree)
    float mx[4];
#pragma unroll
    for (int nk = 0; nk < 4; nk++)
      mx[nk] = fmaxf(fmaxf(sc[nk][0], sc[nk][1]), fmaxf(sc[nk][2], sc[nk][3]));
    float smax = fmaxf(fmaxf(mx[0], mx[1]), fmaxf(mx[2], mx[3]));
    smax = redmax_lg(smax);
    const bool defer = __all(smax - mrun <= 11.0f);
    const float mn = defer ? mrun : fmaxf(mrun, smax);
    float psum = 0.0f;
#pragma unroll
    for (int nk = 0; nk < 4; nk++)
#pragma unroll
      for (int r = 0; r < 4; r++) {
        float p = exp2_hw(sc[nk][r] - mn);
        sc[nk][r] = p;
        psum += p;
      }
    psum = redsum_lg(psum);
    if (defer) {
      lrun += psum;
    } else {
      const float so = exp2_hw(mrun - mn);
      lrun = lrun * so + psum;
      mrun = mn;
#pragma unroll
      for (int nd = 0; nd < 4; nd++)
#pragma unroll
        for (int r = 0; r < 4; r++) octx[nd][r] *= so;
    }
    // P^T -> PV B-fragments via cvt_pk + permlane swaps; PV: O^T += V^T * P^T
#pragma unroll
    for (int kk = 0; kk < 2; kk++) {
      u32 a0 = cvtpk(sc[2 * kk][0], sc[2 * kk][1]);
      u32 a1 = cvtpk(sc[2 * kk][2], sc[2 * kk][3]);
      u32 b0 = cvtpk(sc[2 * kk + 1][0], sc[2 * kk + 1][1]);
      u32 b1 = cvtpk(sc[2 * kk + 1][2], sc[2 * kk + 1][3]);
      plswap32(a0, b0);
      plswap32(a1, b1);
      plswap16(a0, b0);
      plswap16(a1, b1);
      u32x4 wv = {a0, a1, b0, b1};
      bf16x8 pfrag = __builtin_bit_cast(bf16x8, wv);
#pragma unroll
      for (int nd = 0; nd < 4; nd++) {
        bf16x8 vf = *(const bf16x8*)(bV + (nd * 16 + l15) * 64 + (c0 ^ (kk * 32)));
        octx[nd] = MFMA16(vf, pfrag, octx[nd]);
      }
    }
  }
  const float inv = 1.0f / lrun;
  u16* cb = ctx + (size_t)b * 1048576 + (size_t)(q0 + l15) * 1024 + h * 64 + lg * 4;
#pragma unroll
  for (int nd = 0; nd < 4; nd++) {
    *(ushort4*)(cb + nd * 16) = make_ushort4(f2bf(octx[nd][0] * inv), f2bf(octx[nd][1] * inv),
                                             f2bf(octx[nd][2] * inv), f2bf(octx[nd][3] * inv));
  }
}

extern "C" void kernel_launch(void* const* d_in, const int* in_sizes, int n_in,
                              void* d_out, int out_size, void* d_ws, size_t ws_size,
                              hipStream_t stream) {
  (void)in_sizes; (void)n_in; (void)out_size; (void)ws_size;
  const float* Q  = (const float*)d_in[0];
  const float* K  = (const float*)d_in[1];
  const float* V  = (const float*)d_in[2];
  const float* tok = (const float*)d_in[3];
  const float* st  = (const float*)d_in[4];
  const float* df  = (const float*)d_in[5];
  const float* cf  = (const float*)d_in[6];
  const int*   msk = (const int*)d_in[8];
  const float* Wq = (const float*)d_in[9];
  const float* bq = (const float*)d_in[10];
  const float* Wk = (const float*)d_in[11];
  const float* bk = (const float*)d_in[12];
  const float* Wv = (const float*)d_in[13];
  const float* bv = (const float*)d_in[14];
  const float* Wo = (const float*)d_in[15];
  const float* bo = (const float*)d_in[16];

  char* ws = (char*)d_ws;
  const size_t MB = 1ull << 20;
  u16* Qbf = (u16*)(ws);            // 3 x 8 MB, stride 8 MB (Q,K,V)
  u16* Wqb = (u16*)(ws + 24 * MB);  // 4 x 2 MB, stride 2 MB (Wq,Wk,Wv,Wo)
  u8*  pkQ = (u8*)(ws + 32 * MB);   // 4 MB packed masks
  u16* Qh  = (u16*)(ws + 36 * MB);  // 3 x 8 MB, stride 8 MB (Qh,Kh,VhT)
  u16* ctx = (u16*)(ws + 60 * MB);
  u16* Kbf = Qbf + 4194304;
  u16* Vbf = Qbf + 8388608;
  u16* Wkb = Wqb + 1048576;
  u16* Wvb = Wqb + 2097152;
  u16* Wob = Wqb + 3145728;

  cvt_all<<<5120, 256, 0, stream>>>((const float4*)Q, (const float4*)K, (const float4*)V,
                                    (const float4*)Wq, (const float4*)Wk, (const float4*)Wv, (const float4*)Wo,
                                    (ushort4*)Qbf, (ushort4*)Kbf, (ushort4*)Vbf,
                                    (ushort4*)Wqb, (ushort4*)Wkb, (ushort4*)Wvb, (ushort4*)Wob);
  pack_kernel<<<1024, 256, 0, stream>>>((const float4*)tok, (const float4*)st, (const float4*)df,
                                        (const float4*)cf, (const int4*)msk, (u32*)pkQ);
  gemm_qkv<<<dim3(8, 32, 3), 256, 0, stream>>>(Qbf, Wqb, bq, bk, bv, Qh);
  attn_kernel<<<1024, 256, 0, stream>>>(Qh, Qh + 4194304, Qh + 8388608, pkQ, ctx);
  gemm_out<<<dim3(8, 32), 256, 0, stream>>>(ctx, Wob, bo, (float*)d_out);
}

// Round 6
// 153.922 us; speedup vs baseline: 1.8444x; 1.0512x over previous
//
#include <hip/hip_runtime.h>
#include <stdint.h>

typedef unsigned short u16;
typedef unsigned int   u32;
typedef unsigned char  u8;
typedef __attribute__((ext_vector_type(4))) float f32x4;
typedef __attribute__((ext_vector_type(8))) __bf16 bf16x8;
typedef __attribute__((ext_vector_type(2))) unsigned int u32x2;
typedef __attribute__((ext_vector_type(4))) unsigned int u32x4;

#define MFMA16(a, b, c) __builtin_amdgcn_mfma_f32_16x16x32_bf16((a), (b), (c), 0, 0, 0)

__device__ __forceinline__ u16 f2bf(float f) {
  u32 u = __float_as_uint(f);
  return (u16)((u + 0x7fffu + ((u >> 16) & 1u)) >> 16);  // RNE
}

__device__ __forceinline__ void gl_lds16(const void* g, void* l) {
  __builtin_amdgcn_global_load_lds((const __attribute__((address_space(1))) u32*)g,
                                   (__attribute__((address_space(3))) u32*)l, 16, 0, 0);
}

__device__ __forceinline__ u32 cvtpk(float a, float b) {
  u32 r;
  asm("v_cvt_pk_bf16_f32 %0, %1, %2" : "=v"(r) : "v"(a), "v"(b));
  return r;
}

__device__ __forceinline__ float exp2_hw(float x) {  // v_exp_f32 = 2^x
  float r;
  asm("v_exp_f32 %0, %1" : "=v"(r) : "v"(x));
  return r;
}

__device__ __forceinline__ void plswap32(u32& x, u32& y) {
  u32x2 r = __builtin_amdgcn_permlane32_swap(x, y, false, false);
  x = r.x; y = r.y;
}
__device__ __forceinline__ void plswap16(u32& x, u32& y) {
  u32x2 r = __builtin_amdgcn_permlane16_swap(x, y, false, false);
  x = r.x; y = r.y;
}

__device__ __forceinline__ float redmax_lg(float v) {
  u32 x = __float_as_uint(v), y = x;
  plswap16(x, y);
  float m = fmaxf(__uint_as_float(x), __uint_as_float(y));
  u32 a = __float_as_uint(m), b = a;
  plswap32(a, b);
  return fmaxf(__uint_as_float(a), __uint_as_float(b));
}
__device__ __forceinline__ float redsum_lg(float v) {
  u32 x = __float_as_uint(v), y = x;
  plswap16(x, y);
  float m = __uint_as_float(x) + __uint_as_float(y);
  u32 a = __float_as_uint(m), b = a;
  plswap32(a, b);
  return __uint_as_float(a) + __uint_as_float(b);
}

// ---------------- fused prep: f32->bf16 (QKV + weights) AND mask packing ----------------
// bits: 0=token 1=stmt 2=df 3=cf 4=mask!=0 5=token|!mask 6=stmt|!mask 7=!mask
__device__ __forceinline__ u32 pbit(float t, float s, float d, float c, int m) {
  const u32 nm = (m == 0) ? 1u : 0u;
  u32 r = (t != 0.0f ? 1u : 0u) | (s != 0.0f ? 2u : 0u) | (d != 0.0f ? 4u : 0u) |
          (c != 0.0f ? 8u : 0u) | ((1u - nm) << 4);
  r |= (((t != 0.0f ? 1u : 0u) | nm) << 5) | (((s != 0.0f ? 1u : 0u) | nm) << 6) | (nm << 7);
  return r;
}

__global__ void __launch_bounds__(256) prep_kernel(
    const float4* __restrict__ Q, const float4* __restrict__ K, const float4* __restrict__ V,
    const float4* __restrict__ Wq, const float4* __restrict__ Wk, const float4* __restrict__ Wv,
    const float4* __restrict__ Wo, ushort4* __restrict__ oQ, ushort4* __restrict__ oK,
    ushort4* __restrict__ oV, ushort4* __restrict__ oWq, ushort4* __restrict__ oWk,
    ushort4* __restrict__ oWv, ushort4* __restrict__ oWo,
    const float4* __restrict__ tok, const float4* __restrict__ st, const float4* __restrict__ df,
    const float4* __restrict__ cf, const int4* __restrict__ msk, u32* __restrict__ pko) {
  const int bid = blockIdx.x;
  float4 v;
  if (bid < 4096) {  // QKV cvt: 1048576 float4 per stream
    const int i = bid * 256 + threadIdx.x;
    v = Q[i]; oQ[i] = make_ushort4(f2bf(v.x), f2bf(v.y), f2bf(v.z), f2bf(v.w));
    v = K[i]; oK[i] = make_ushort4(f2bf(v.x), f2bf(v.y), f2bf(v.z), f2bf(v.w));
    v = V[i]; oV[i] = make_ushort4(f2bf(v.x), f2bf(v.y), f2bf(v.z), f2bf(v.w));
  } else if (bid < 5120) {  // weights cvt: 262144 float4 per stream
    const int j = (bid - 4096) * 256 + threadIdx.x;
    v = Wq[j]; oWq[j] = make_ushort4(f2bf(v.x), f2bf(v.y), f2bf(v.z), f2bf(v.w));
    v = Wk[j]; oWk[j] = make_ushort4(f2bf(v.x), f2bf(v.y), f2bf(v.z), f2bf(v.w));
    v = Wv[j]; oWv[j] = make_ushort4(f2bf(v.x), f2bf(v.y), f2bf(v.z), f2bf(v.w));
    v = Wo[j]; oWo[j] = make_ushort4(f2bf(v.x), f2bf(v.y), f2bf(v.z), f2bf(v.w));
  } else {  // pack: 16 mask elements per thread
    const int i = (bid - 5120) * 256 + threadIdx.x;
    const int b = i >> 16, rem = i & 65535, q = rem >> 6, kc = rem & 63;
    const u32 base = ((u32)(b * 64 + (q >> 4)) * 16 + (kc >> 2)) * 256 + (q & 15) * 16 + (kc & 3);
#pragma unroll
    for (int j = 0; j < 4; j++) {
      float4 vt = tok[i * 4 + j], vs = st[i * 4 + j], vd = df[i * 4 + j], vc = cf[i * 4 + j];
      int4 vm = msk[i * 4 + j];
      u32 b0 = pbit(vt.x, vs.x, vd.x, vc.x, vm.x);
      u32 b1 = pbit(vt.y, vs.y, vd.y, vc.y, vm.y);
      u32 b2 = pbit(vt.z, vs.z, vd.z, vc.z, vm.z);
      u32 b3 = pbit(vt.w, vs.w, vd.w, vc.w, vm.w);
      pko[base + j * 4] = b0 | (b1 << 8) | (b2 << 16) | (b3 << 24);
    }
  }
}

// ---------------- batched QKV projection GEMM, XCD-local block mapping ----------------
// grid = 768 (1D). l = (f&7)*96 + (f>>3): XCD i owns 96 consecutive logical blocks
// (12 contiguous m-panels x 8 n), so each A-panel is fetched by exactly one XCD.
// z<2: write bf16 head-major  out[(b*16+h)*65536 + s*64 + d]
// z=2: write bf16 transposed  out[(b*16+h)*65536 + d*1024 + s]
__global__ void __launch_bounds__(256) gemm_qkv(const u16* __restrict__ Abase, const u16* __restrict__ Wbase,
                                                const float* __restrict__ bq, const float* __restrict__ bk,
                                                const float* __restrict__ bv, u16* __restrict__ Obase) {
  __shared__ u16 smA[128 * 32];
  __shared__ u16 smB[128 * 32];
  const int fb = blockIdx.x;
  const int lid = (fb & 7) * 96 + (fb >> 3);
  const int z = lid >> 8;
  const int m0 = ((lid & 255) >> 3) * 128;
  const int n0 = (lid & 7) * 128;
  const u16* A = Abase + (size_t)z * 4194304;
  const u16* W = Wbase + (size_t)z * 1048576;
  const float* bias = (z == 0) ? bq : (z == 1) ? bk : bv;
  u16* Out = Obase + (size_t)z * 4194304;
  const int t = threadIdx.x;
  const int w = t >> 6, l = t & 63;
  const int l15 = l & 15, lg = l >> 4;
  const int wr = w >> 1, wc = w & 1;
  f32x4 acc[4][4] = {};
  const int srow = w * 16 + (l >> 2);
  const int scol = (l & 3) * 8;
  const u16* Ab = A + (size_t)(m0 + srow) * 1024 + scol;
  const u16* Wb = W + (size_t)(n0 + srow) * 1024 + scol;
  u16* sA0 = smA + srow * 32 + scol;
  u16* sB0 = smB + srow * 32 + scol;
  for (int kk = 0; kk < 1024; kk += 32) {
    gl_lds16(Ab + kk, sA0);
    gl_lds16(Ab + kk + (size_t)64 * 1024, sA0 + 64 * 32);
    gl_lds16(Wb + kk, sB0);
    gl_lds16(Wb + kk + (size_t)64 * 1024, sB0 + 64 * 32);
    __syncthreads();
    bf16x8 af[4], bv_[4];
#pragma unroll
    for (int i = 0; i < 4; i++) af[i] = *(const bf16x8*)(smA + (wr * 64 + i * 16 + l15) * 32 + lg * 8);
#pragma unroll
    for (int i = 0; i < 4; i++) bv_[i] = *(const bf16x8*)(smB + (wc * 64 + i * 16 + l15) * 32 + lg * 8);
#pragma unroll
    for (int i = 0; i < 4; i++)
#pragma unroll
      for (int j = 0; j < 4; j++) acc[i][j] = MFMA16(af[i], bv_[j], acc[i][j]);
    __syncthreads();
  }
#pragma unroll
  for (int j = 0; j < 4; j++) {
    const int n = n0 + wc * 64 + j * 16 + l15;
    const float bvj = bias[n];
#pragma unroll
    for (int i = 0; i < 4; i++) {
      const int mbase = m0 + wr * 64 + i * 16 + lg * 4;
      if (z < 2) {
#pragma unroll
        for (int r = 0; r < 4; r++) {
          const int m = mbase + r;
          Out[((size_t)((m >> 10) * 16 + (n >> 6)) << 16) + (size_t)(m & 1023) * 64 + (n & 63)] =
              f2bf(acc[i][j][r] + bvj);
        }
      } else {
        size_t off = ((size_t)((mbase >> 10) * 16 + (n >> 6)) << 16) + (size_t)(n & 63) * 1024 + (mbase & 1023);
        *(ushort4*)(Out + off) = make_ushort4(f2bf(acc[i][j][0] + bvj), f2bf(acc[i][j][1] + bvj),
                                              f2bf(acc[i][j][2] + bvj), f2bf(acc[i][j][3] + bvj));
      }
    }
  }
}

// ---------------- output projection GEMM (f32 out), XCD-local block mapping ----------------
__global__ void __launch_bounds__(256) gemm_out(const u16* __restrict__ A, const u16* __restrict__ W,
                                                const float* __restrict__ bias, float* __restrict__ Out) {
  __shared__ u16 smA[128 * 32];
  __shared__ u16 smB[128 * 32];
  const int fb = blockIdx.x;
  const int lid = (fb & 7) * 32 + (fb >> 3);
  const int m0 = (lid >> 3) * 128;
  const int n0 = (lid & 7) * 128;
  const int t = threadIdx.x;
  const int w = t >> 6, l = t & 63;
  const int l15 = l & 15, lg = l >> 4;
  const int wr = w >> 1, wc = w & 1;
  f32x4 acc[4][4] = {};
  const int srow = w * 16 + (l >> 2);
  const int scol = (l & 3) * 8;
  const u16* Ab = A + (size_t)(m0 + srow) * 1024 + scol;
  const u16* Wb = W + (size_t)(n0 + srow) * 1024 + scol;
  u16* sA0 = smA + srow * 32 + scol;
  u16* sB0 = smB + srow * 32 + scol;
  for (int kk = 0; kk < 1024; kk += 32) {
    gl_lds16(Ab + kk, sA0);
    gl_lds16(Ab + kk + (size_t)64 * 1024, sA0 + 64 * 32);
    gl_lds16(Wb + kk, sB0);
    gl_lds16(Wb + kk + (size_t)64 * 1024, sB0 + 64 * 32);
    __syncthreads();
    bf16x8 af[4], bv_[4];
#pragma unroll
    for (int i = 0; i < 4; i++) af[i] = *(const bf16x8*)(smA + (wr * 64 + i * 16 + l15) * 32 + lg * 8);
#pragma unroll
    for (int i = 0; i < 4; i++) bv_[i] = *(const bf16x8*)(smB + (wc * 64 + i * 16 + l15) * 32 + lg * 8);
#pragma unroll
    for (int i = 0; i < 4; i++)
#pragma unroll
      for (int j = 0; j < 4; j++) acc[i][j] = MFMA16(af[i], bv_[j], acc[i][j]);
    __syncthreads();
  }
#pragma unroll
  for (int j = 0; j < 4; j++) {
    const int n = n0 + wc * 64 + j * 16 + l15;
    const float bvj = bias[n];
#pragma unroll
    for (int i = 0; i < 4; i++) {
      const int mbase = m0 + wr * 64 + i * 16 + lg * 4;
#pragma unroll
      for (int r = 0; r < 4; r++) Out[(size_t)(mbase + r) * 1024 + n] = acc[i][j][r] + bvj;
    }
  }
}

// ---------------- flash attention: LDS-staged K/V, log2-domain softmax, T13 defer ----------------
__global__ void __launch_bounds__(256) attn_kernel(const u16* __restrict__ Qp, const u16* __restrict__ Kp,
                                                   const u16* __restrict__ Vt, const u8* __restrict__ pack,
                                                   u16* __restrict__ ctx) {
  __shared__ u16 smK[2][4096];
  __shared__ u16 smV[2][4096];
  const float SCL  = 0.18033688011112042f;  // 0.125 * log2(e)
  const float NEGL = -1.44269504e9f;        // -1e9 * log2(e)
  const int tid = threadIdx.x;
  const int w = tid >> 6, l = tid & 63;
  const int l15 = l & 15, lg = l >> 4;
  const int f = blockIdx.x;
  const int swz = (f & 7) * 128 + (f >> 3);  // bijective XCD swizzle
  const int bh = swz >> 4, bx = swz & 15;
  const int b = bh >> 4, h = bh & 15;
  const int q0 = bx * 64 + w * 16;
  const bool enh = (h >= 8 && h < 12);
  const u32 kbit = (h < 4) ? 0x20u : (h < 8) ? 0x40u : 0x80u;
  const u32 ebit = (h < 10) ? 0x04u : 0x08u;
  const u32 kb_[4] = {kbit, kbit << 8, kbit << 16, kbit << 24};
  const u32 eb_[4] = {ebit, ebit << 8, ebit << 16, ebit << 24};
  const size_t hb = (size_t)bh << 16;

  bf16x8 qf[2];
#pragma unroll
  for (int ks = 0; ks < 2; ks++)
    qf[ks] = *(const bf16x8*)(Qp + hb + (size_t)(q0 + l15) * 64 + ks * 32 + lg * 8);

  const int srow = w * 16 + (l >> 3);
  const int schunk = (l & 7) ^ (l >> 3);
  const u16* Ksrc = Kp + hb + (size_t)srow * 64 + schunk * 8;
  const u16* Vsrc = Vt + hb + (size_t)srow * 1024 + schunk * 8;
  const int c0 = (lg ^ (l15 & 7)) * 8;
  const u8* pkq = pack + ((size_t)((b * 64 + bx * 4 + w) * 16)) * 1024 + (l15 * 4 + lg) * 16;

  gl_lds16(Ksrc, &smK[0][w * 1024]);
  gl_lds16(Ksrc + 512, &smK[0][w * 1024 + 512]);
  gl_lds16(Vsrc, &smV[0][w * 1024]);
  gl_lds16(Vsrc + 8192, &smV[0][w * 1024 + 512]);
  uint4 pk_next = *(const uint4*)(pkq);

  f32x4 octx[4] = {};
  float mrun = -3.0e38f, lrun = 0.0f;

  for (int t = 0; t < 16; t++) {
    __syncthreads();
    const uint4 pkc = pk_next;
    if (t < 15) {
      const int kb = (t + 1) * 64;
      const int nb = (t + 1) & 1;
      gl_lds16(Ksrc + (size_t)kb * 64, &smK[nb][w * 1024]);
      gl_lds16(Ksrc + (size_t)kb * 64 + 512, &smK[nb][w * 1024 + 512]);
      gl_lds16(Vsrc + kb, &smV[nb][w * 1024]);
      gl_lds16(Vsrc + kb + 8192, &smV[nb][w * 1024 + 512]);
      pk_next = *(const uint4*)(pkq + (t + 1) * 1024);
    }
    const u16* bK = smK[t & 1];
    const u16* bV = smV[t & 1];
    f32x4 sc[4];
#pragma unroll
    for (int nk = 0; nk < 4; nk++) {
      const u16* kr = bK + (nk * 16 + l15) * 64;
      bf16x8 kf0 = *(const bf16x8*)(kr + c0);
      bf16x8 kf1 = *(const bf16x8*)(kr + (c0 ^ 32));
      f32x4 z = {0.0f, 0.0f, 0.0f, 0.0f};
      z = MFMA16(kf0, qf[0], z);
      z = MFMA16(kf1, qf[1], z);
      sc[nk] = z;
    }
    const u32 pkw[4] = {pkc.x, pkc.y, pkc.z, pkc.w};
#pragma unroll
    for (int nk = 0; nk < 4; nk++)
#pragma unroll
      for (int r = 0; r < 4; r++) {
        float s = sc[nk][r] * SCL;
        if (enh) s = (pkw[nk] & eb_[r]) ? __builtin_fmaf(fabsf(s), 5.0f, s) : s;
        sc[nk][r] = (pkw[nk] & kb_[r]) ? NEGL : s;
      }
    float mx[4];
#pragma unroll
    for (int nk = 0; nk < 4; nk++)
      mx[nk] = fmaxf(fmaxf(sc[nk][0], sc[nk][1]), fmaxf(sc[nk][2], sc[nk][3]));
    float smax = fmaxf(fmaxf(mx[0], mx[1]), fmaxf(mx[2], mx[3]));
    smax = redmax_lg(smax);
    const bool defer = __all(smax - mrun <= 11.0f);
    const float mn = defer ? mrun : fmaxf(mrun, smax);
    float psum = 0.0f;
#pragma unroll
    for (int nk = 0; nk < 4; nk++)
#pragma unroll
      for (int r = 0; r < 4; r++) {
        float p = exp2_hw(sc[nk][r] - mn);
        sc[nk][r] = p;
        psum += p;
      }
    psum = redsum_lg(psum);
    if (defer) {
      lrun += psum;
    } else {
      const float so = exp2_hw(mrun - mn);
      lrun = lrun * so + psum;
      mrun = mn;
#pragma unroll
      for (int nd = 0; nd < 4; nd++)
#pragma unroll
        for (int r = 0; r < 4; r++) octx[nd][r] *= so;
    }
#pragma unroll
    for (int kk = 0; kk < 2; kk++) {
      u32 a0 = cvtpk(sc[2 * kk][0], sc[2 * kk][1]);
      u32 a1 = cvtpk(sc[2 * kk][2], sc[2 * kk][3]);
      u32 b0 = cvtpk(sc[2 * kk + 1][0], sc[2 * kk + 1][1]);
      u32 b1 = cvtpk(sc[2 * kk + 1][2], sc[2 * kk + 1][3]);
      plswap32(a0, b0);
      plswap32(a1, b1);
      plswap16(a0, b0);
      plswap16(a1, b1);
      u32x4 wv = {a0, a1, b0, b1};
      bf16x8 pfrag = __builtin_bit_cast(bf16x8, wv);
#pragma unroll
      for (int nd = 0; nd < 4; nd++) {
        bf16x8 vf = *(const bf16x8*)(bV + (nd * 16 + l15) * 64 + (c0 ^ (kk * 32)));
        octx[nd] = MFMA16(vf, pfrag, octx[nd]);
      }
    }
  }
  const float inv = 1.0f / lrun;
  u16* cb = ctx + (size_t)b * 1048576 + (size_t)(q0 + l15) * 1024 + h * 64 + lg * 4;
#pragma unroll
  for (int nd = 0; nd < 4; nd++) {
    *(ushort4*)(cb + nd * 16) = make_ushort4(f2bf(octx[nd][0] * inv), f2bf(octx[nd][1] * inv),
                                             f2bf(octx[nd][2] * inv), f2bf(octx[nd][3] * inv));
  }
}

extern "C" void kernel_launch(void* const* d_in, const int* in_sizes, int n_in,
                              void* d_out, int out_size, void* d_ws, size_t ws_size,
                              hipStream_t stream) {
  (void)in_sizes; (void)n_in; (void)out_size; (void)ws_size;
  const float* Q  = (const float*)d_in[0];
  const float* K  = (const float*)d_in[1];
  const float* V  = (const float*)d_in[2];
  const float* tok = (const float*)d_in[3];
  const float* st  = (const float*)d_in[4];
  const float* df  = (const float*)d_in[5];
  const float* cf  = (const float*)d_in[6];
  const int*   msk = (const int*)d_in[8];
  const float* Wq = (const float*)d_in[9];
  const float* bq = (const float*)d_in[10];
  const float* Wk = (const float*)d_in[11];
  const float* bk = (const float*)d_in[12];
  const float* Wv = (const float*)d_in[13];
  const float* bv = (const float*)d_in[14];
  const float* Wo = (const float*)d_in[15];
  const float* bo = (const float*)d_in[16];

  char* ws = (char*)d_ws;
  const size_t MB = 1ull << 20;
  u16* Qbf = (u16*)(ws);            // 3 x 8 MB, stride 8 MB (Q,K,V)
  u16* Wqb = (u16*)(ws + 24 * MB);  // 4 x 2 MB, stride 2 MB (Wq,Wk,Wv,Wo)
  u8*  pkQ = (u8*)(ws + 32 * MB);   // 4 MB packed masks
  u16* Qh  = (u16*)(ws + 36 * MB);  // 3 x 8 MB, stride 8 MB (Qh,Kh,VhT)
  u16* ctx = (u16*)(ws + 60 * MB);
  u16* Kbf = Qbf + 4194304;
  u16* Vbf = Qbf + 8388608;
  u16* Wkb = Wqb + 1048576;
  u16* Wvb = Wqb + 2097152;
  u16* Wob = Wqb + 3145728;

  prep_kernel<<<6144, 256, 0, stream>>>(
      (const float4*)Q, (const float4*)K, (const float4*)V, (const float4*)Wq, (const float4*)Wk,
      (const float4*)Wv, (const float4*)Wo, (ushort4*)Qbf, (ushort4*)Kbf, (ushort4*)Vbf,
      (ushort4*)Wqb, (ushort4*)Wkb, (ushort4*)Wvb, (ushort4*)Wob,
      (const float4*)tok, (const float4*)st, (const float4*)df, (const float4*)cf,
      (const int4*)msk, (u32*)pkQ);
  gemm_qkv<<<768, 256, 0, stream>>>(Qbf, Wqb, bq, bk, bv, Qh);
  attn_kernel<<<1024, 256, 0, stream>>>(Qh, Qh + 4194304, Qh + 8388608, pkQ, ctx);
  gemm_out<<<256, 256, 0, stream>>>(ctx, Wob, bo, (float*)d_out);
}

// Round 7
// 148.751 us; speedup vs baseline: 1.9085x; 1.0348x over previous
//
#include <hip/hip_runtime.h>
#include <stdint.h>

typedef unsigned short u16;
typedef unsigned int   u32;
typedef unsigned char  u8;
typedef __attribute__((ext_vector_type(4))) float f32x4;
typedef __attribute__((ext_vector_type(8))) __bf16 bf16x8;
typedef __attribute__((ext_vector_type(2))) unsigned int u32x2;
typedef __attribute__((ext_vector_type(4))) unsigned int u32x4;

#define MFMA16(a, b, c) __builtin_amdgcn_mfma_f32_16x16x32_bf16((a), (b), (c), 0, 0, 0)

__device__ __forceinline__ u16 f2bf(float f) {
  u32 u = __float_as_uint(f);
  return (u16)((u + 0x7fffu + ((u >> 16) & 1u)) >> 16);  // RNE
}

__device__ __forceinline__ void gl_lds16(const void* g, void* l) {
  __builtin_amdgcn_global_load_lds((const __attribute__((address_space(1))) u32*)g,
                                   (__attribute__((address_space(3))) u32*)l, 16, 0, 0);
}

__device__ __forceinline__ u32 cvtpk(float a, float b) {
  u32 r;
  asm("v_cvt_pk_bf16_f32 %0, %1, %2" : "=v"(r) : "v"(a), "v"(b));
  return r;
}

__device__ __forceinline__ float exp2_hw(float x) {  // v_exp_f32 = 2^x
  float r;
  asm("v_exp_f32 %0, %1" : "=v"(r) : "v"(x));
  return r;
}

__device__ __forceinline__ void plswap32(u32& x, u32& y) {
  u32x2 r = __builtin_amdgcn_permlane32_swap(x, y, false, false);
  x = r.x; y = r.y;
}
__device__ __forceinline__ void plswap16(u32& x, u32& y) {
  u32x2 r = __builtin_amdgcn_permlane16_swap(x, y, false, false);
  x = r.x; y = r.y;
}

__device__ __forceinline__ float redmax_lg(float v) {
  u32 x = __float_as_uint(v), y = x;
  plswap16(x, y);
  float m = fmaxf(__uint_as_float(x), __uint_as_float(y));
  u32 a = __float_as_uint(m), b = a;
  plswap32(a, b);
  return fmaxf(__uint_as_float(a), __uint_as_float(b));
}
__device__ __forceinline__ float redsum_lg(float v) {
  u32 x = __float_as_uint(v), y = x;
  plswap16(x, y);
  float m = __uint_as_float(x) + __uint_as_float(y);
  u32 a = __float_as_uint(m), b = a;
  plswap32(a, b);
  return __uint_as_float(a) + __uint_as_float(b);
}

// ---------------- fused prep: f32->bf16 (QKV + weights) AND mask packing ----------------
// pack bits: 0=token 1=stmt 2=df 3=cf 4=mask!=0 5=token|!mask 6=stmt|!mask 7=!mask
__device__ __forceinline__ u32 pbit(float t, float s, float d, float c, int m) {
  const u32 nm = (m == 0) ? 1u : 0u;
  u32 r = (t != 0.0f ? 1u : 0u) | (s != 0.0f ? 2u : 0u) | (d != 0.0f ? 4u : 0u) |
          (c != 0.0f ? 8u : 0u) | ((1u - nm) << 4);
  r |= (((t != 0.0f ? 1u : 0u) | nm) << 5) | (((s != 0.0f ? 1u : 0u) | nm) << 6) | (nm << 7);
  return r;
}

__global__ void __launch_bounds__(256) prep_kernel(
    const float4* __restrict__ Q, const float4* __restrict__ K, const float4* __restrict__ V,
    const float4* __restrict__ Wq, const float4* __restrict__ Wk, const float4* __restrict__ Wv,
    const float4* __restrict__ Wo, ushort4* __restrict__ oQ, ushort4* __restrict__ oK,
    ushort4* __restrict__ oV, ushort4* __restrict__ oWq, ushort4* __restrict__ oWk,
    ushort4* __restrict__ oWv, ushort4* __restrict__ oWo,
    const float4* __restrict__ tok, const float4* __restrict__ st, const float4* __restrict__ df,
    const float4* __restrict__ cf, const int4* __restrict__ msk, u32* __restrict__ pko) {
  const int bid = blockIdx.x;
  float4 v;
  if (bid < 2048) {  // QKV cvt: 1048576 float4 per stream, 2 per thread
    const int i = bid * 512 + threadIdx.x;
#pragma unroll
    for (int u = 0; u < 2; u++) {
      const int k = i + u * 256;
      v = Q[k]; oQ[k] = make_ushort4(f2bf(v.x), f2bf(v.y), f2bf(v.z), f2bf(v.w));
      v = K[k]; oK[k] = make_ushort4(f2bf(v.x), f2bf(v.y), f2bf(v.z), f2bf(v.w));
      v = V[k]; oV[k] = make_ushort4(f2bf(v.x), f2bf(v.y), f2bf(v.z), f2bf(v.w));
    }
  } else if (bid < 2560) {  // weights cvt: 262144 float4 per stream, 2 per thread
    const int j = (bid - 2048) * 512 + threadIdx.x;
#pragma unroll
    for (int u = 0; u < 2; u++) {
      const int k = j + u * 256;
      v = Wq[k]; oWq[k] = make_ushort4(f2bf(v.x), f2bf(v.y), f2bf(v.z), f2bf(v.w));
      v = Wk[k]; oWk[k] = make_ushort4(f2bf(v.x), f2bf(v.y), f2bf(v.z), f2bf(v.w));
      v = Wv[k]; oWv[k] = make_ushort4(f2bf(v.x), f2bf(v.y), f2bf(v.z), f2bf(v.w));
      v = Wo[k]; oWo[k] = make_ushort4(f2bf(v.x), f2bf(v.y), f2bf(v.z), f2bf(v.w));
    }
  } else {  // pack: one float4 (4 consecutive k) -> one u32 word, fully coalesced
    const int i = (bid - 2560) * 256 + threadIdx.x;  // float4 index over (b,q,k4)
    const int b = i >> 18, rem = i & 262143, q = rem >> 8, k4 = rem & 255;
    const int t = k4 >> 4, nk = (k4 >> 2) & 3, lg = k4 & 3;
    const u32 widx = ((u32)(b * 64 + (q >> 4)) * 16 + t) * 256 + (q & 15) * 16 + lg * 4 + nk;
    float4 vt = tok[i], vs = st[i], vd = df[i], vc = cf[i];
    int4 vm = msk[i];
    u32 b0 = pbit(vt.x, vs.x, vd.x, vc.x, vm.x);
    u32 b1 = pbit(vt.y, vs.y, vd.y, vc.y, vm.y);
    u32 b2 = pbit(vt.z, vs.z, vd.z, vc.z, vm.z);
    u32 b3 = pbit(vt.w, vs.w, vd.w, vc.w, vm.w);
    pko[widx] = b0 | (b1 << 8) | (b2 << 16) | (b3 << 24);
  }
}

// ---------------- batched QKV projection GEMM, XCD-local block mapping ----------------
// grid = 768 (1D). l = (f&7)*96 + (f>>3): XCD i owns 96 consecutive logical blocks
// (12 contiguous m-panels x 8 n), so each A-panel is fetched by exactly one XCD.
// z<2: write bf16 head-major  out[(b*16+h)*65536 + s*64 + d]
// z=2: write bf16 transposed  out[(b*16+h)*65536 + d*1024 + s]
__global__ void __launch_bounds__(256) gemm_qkv(const u16* __restrict__ Abase, const u16* __restrict__ Wbase,
                                                const float* __restrict__ bq, const float* __restrict__ bk,
                                                const float* __restrict__ bv, u16* __restrict__ Obase) {
  __shared__ u16 smA[128 * 32];
  __shared__ u16 smB[128 * 32];
  const int fb = blockIdx.x;
  const int lid = (fb & 7) * 96 + (fb >> 3);
  const int z = lid >> 8;
  const int m0 = ((lid & 255) >> 3) * 128;
  const int n0 = (lid & 7) * 128;
  const u16* A = Abase + (size_t)z * 4194304;
  const u16* W = Wbase + (size_t)z * 1048576;
  const float* bias = (z == 0) ? bq : (z == 1) ? bk : bv;
  u16* Out = Obase + (size_t)z * 4194304;
  const int t = threadIdx.x;
  const int w = t >> 6, l = t & 63;
  const int l15 = l & 15, lg = l >> 4;
  const int wr = w >> 1, wc = w & 1;
  f32x4 acc[4][4] = {};
  const int srow = w * 16 + (l >> 2);
  const int scol = (l & 3) * 8;
  const u16* Ab = A + (size_t)(m0 + srow) * 1024 + scol;
  const u16* Wb = W + (size_t)(n0 + srow) * 1024 + scol;
  u16* sA0 = smA + srow * 32 + scol;
  u16* sB0 = smB + srow * 32 + scol;
  for (int kk = 0; kk < 1024; kk += 32) {
    gl_lds16(Ab + kk, sA0);
    gl_lds16(Ab + kk + (size_t)64 * 1024, sA0 + 64 * 32);
    gl_lds16(Wb + kk, sB0);
    gl_lds16(Wb + kk + (size_t)64 * 1024, sB0 + 64 * 32);
    __syncthreads();
    bf16x8 af[4], bv_[4];
#pragma unroll
    for (int i = 0; i < 4; i++) af[i] = *(const bf16x8*)(smA + (wr * 64 + i * 16 + l15) * 32 + lg * 8);
#pragma unroll
    for (int i = 0; i < 4; i++) bv_[i] = *(const bf16x8*)(smB + (wc * 64 + i * 16 + l15) * 32 + lg * 8);
#pragma unroll
    for (int i = 0; i < 4; i++)
#pragma unroll
      for (int j = 0; j < 4; j++) acc[i][j] = MFMA16(af[i], bv_[j], acc[i][j]);
    __syncthreads();
  }
#pragma unroll
  for (int j = 0; j < 4; j++) {
    const int n = n0 + wc * 64 + j * 16 + l15;
    const float bvj = bias[n];
#pragma unroll
    for (int i = 0; i < 4; i++) {
      const int mbase = m0 + wr * 64 + i * 16 + lg * 4;
      if (z < 2) {
#pragma unroll
        for (int r = 0; r < 4; r++) {
          const int m = mbase + r;
          Out[((size_t)((m >> 10) * 16 + (n >> 6)) << 16) + (size_t)(m & 1023) * 64 + (n & 63)] =
              f2bf(acc[i][j][r] + bvj);
        }
      } else {
        size_t off = ((size_t)((mbase >> 10) * 16 + (n >> 6)) << 16) + (size_t)(n & 63) * 1024 + (mbase & 1023);
        *(ushort4*)(Out + off) = make_ushort4(f2bf(acc[i][j][0] + bvj), f2bf(acc[i][j][1] + bvj),
                                              f2bf(acc[i][j][2] + bvj), f2bf(acc[i][j][3] + bvj));
      }
    }
  }
}

// ---------------- output projection GEMM (f32 out), XCD-local block mapping ----------------
__global__ void __launch_bounds__(256) gemm_out(const u16* __restrict__ A, const u16* __restrict__ W,
                                                const float* __restrict__ bias, float* __restrict__ Out) {
  __shared__ u16 smA[128 * 32];
  __shared__ u16 smB[128 * 32];
  const int fb = blockIdx.x;
  const int lid = (fb & 7) * 32 + (fb >> 3);
  const int m0 = (lid >> 3) * 128;
  const int n0 = (lid & 7) * 128;
  const int t = threadIdx.x;
  const int w = t >> 6, l = t & 63;
  const int l15 = l & 15, lg = l >> 4;
  const int wr = w >> 1, wc = w & 1;
  f32x4 acc[4][4] = {};
  const int srow = w * 16 + (l >> 2);
  const int scol = (l & 3) * 8;
  const u16* Ab = A + (size_t)(m0 + srow) * 1024 + scol;
  const u16* Wb = W + (size_t)(n0 + srow) * 1024 + scol;
  u16* sA0 = smA + srow * 32 + scol;
  u16* sB0 = smB + srow * 32 + scol;
  for (int kk = 0; kk < 1024; kk += 32) {
    gl_lds16(Ab + kk, sA0);
    gl_lds16(Ab + kk + (size_t)64 * 1024, sA0 + 64 * 32);
    gl_lds16(Wb + kk, sB0);
    gl_lds16(Wb + kk + (size_t)64 * 1024, sB0 + 64 * 32);
    __syncthreads();
    bf16x8 af[4], bv_[4];
#pragma unroll
    for (int i = 0; i < 4; i++) af[i] = *(const bf16x8*)(smA + (wr * 64 + i * 16 + l15) * 32 + lg * 8);
#pragma unroll
    for (int i = 0; i < 4; i++) bv_[i] = *(const bf16x8*)(smB + (wc * 64 + i * 16 + l15) * 32 + lg * 8);
#pragma unroll
    for (int i = 0; i < 4; i++)
#pragma unroll
      for (int j = 0; j < 4; j++) acc[i][j] = MFMA16(af[i], bv_[j], acc[i][j]);
    __syncthreads();
  }
#pragma unroll
  for (int j = 0; j < 4; j++) {
    const int n = n0 + wc * 64 + j * 16 + l15;
    const float bvj = bias[n];
#pragma unroll
    for (int i = 0; i < 4; i++) {
      const int mbase = m0 + wr * 64 + i * 16 + lg * 4;
#pragma unroll
      for (int r = 0; r < 4; r++) Out[(size_t)(mbase + r) * 1024 + n] = acc[i][j][r] + bvj;
    }
  }
}

// ---------------- flash attention: LDS-staged K/V, log2-domain softmax, T13 defer ----------------
__global__ void __launch_bounds__(256) attn_kernel(const u16* __restrict__ Qp, const u16* __restrict__ Kp,
                                                   const u16* __restrict__ Vt, const u8* __restrict__ pack,
                                                   u16* __restrict__ ctx) {
  __shared__ u16 smK[2][4096];
  __shared__ u16 smV[2][4096];
  const float SCL  = 0.18033688011112042f;  // 0.125 * log2(e)
  const float NEGL = -1.44269504e9f;        // -1e9 * log2(e)
  const int tid = threadIdx.x;
  const int w = tid >> 6, l = tid & 63;
  const int l15 = l & 15, lg = l >> 4;
  const int f = blockIdx.x;
  const int swz = (f & 7) * 128 + (f >> 3);  // bijective XCD swizzle
  const int bh = swz >> 4, bx = swz & 15;
  const int b = bh >> 4, h = bh & 15;
  const int q0 = bx * 64 + w * 16;
  const bool enh = (h >= 8 && h < 12);
  const u32 kbit = (h < 4) ? 0x20u : (h < 8) ? 0x40u : 0x80u;
  const u32 ebit = (h < 10) ? 0x04u : 0x08u;
  const u32 kb_[4] = {kbit, kbit << 8, kbit << 16, kbit << 24};
  const u32 eb_[4] = {ebit, ebit << 8, ebit << 16, ebit << 24};
  const size_t hb = (size_t)bh << 16;

  bf16x8 qf[2];
#pragma unroll
  for (int ks = 0; ks < 2; ks++)
    qf[ks] = *(const bf16x8*)(Qp + hb + (size_t)(q0 + l15) * 64 + ks * 32 + lg * 8);

  const int srow = w * 16 + (l >> 3);
  const int schunk = (l & 7) ^ (l >> 3);
  const u16* Ksrc = Kp + hb + (size_t)srow * 64 + schunk * 8;
  const u16* Vsrc = Vt + hb + (size_t)srow * 1024 + schunk * 8;
  const int c0 = (lg ^ (l15 & 7)) * 8;
  const u8* pkq = pack + ((size_t)((b * 64 + bx * 4 + w) * 16)) * 1024 + (l15 * 4 + lg) * 16;

  gl_lds16(Ksrc, &smK[0][w * 1024]);
  gl_lds16(Ksrc + 512, &smK[0][w * 1024 + 512]);
  gl_lds16(Vsrc, &smV[0][w * 1024]);
  gl_lds16(Vsrc + 8192, &smV[0][w * 1024 + 512]);
  uint4 pk_next = *(const uint4*)(pkq);

  f32x4 octx[4] = {};
  float mrun = -3.0e38f, lrun = 0.0f;

  for (int t = 0; t < 16; t++) {
    __syncthreads();
    const uint4 pkc = pk_next;
    if (t < 15) {
      const int kb = (t + 1) * 64;
      const int nb = (t + 1) & 1;
      gl_lds16(Ksrc + (size_t)kb * 64, &smK[nb][w * 1024]);
      gl_lds16(Ksrc + (size_t)kb * 64 + 512, &smK[nb][w * 1024 + 512]);
      gl_lds16(Vsrc + kb, &smV[nb][w * 1024]);
      gl_lds16(Vsrc + kb + 8192, &smV[nb][w * 1024 + 512]);
      pk_next = *(const uint4*)(pkq + (t + 1) * 1024);
    }
    const u16* bK = smK[t & 1];
    const u16* bV = smV[t & 1];
    f32x4 sc[4];
#pragma unroll
    for (int nk = 0; nk < 4; nk++) {
      const u16* kr = bK + (nk * 16 + l15) * 64;
      bf16x8 kf0 = *(const bf16x8*)(kr + c0);
      bf16x8 kf1 = *(const bf16x8*)(kr + (c0 ^ 32));
      f32x4 z = {0.0f, 0.0f, 0.0f, 0.0f};
      z = MFMA16(kf0, qf[0], z);
      z = MFMA16(kf1, qf[1], z);
      sc[nk] = z;
    }
    const u32 pkw[4] = {pkc.x, pkc.y, pkc.z, pkc.w};
#pragma unroll
    for (int nk = 0; nk < 4; nk++)
#pragma unroll
      for (int r = 0; r < 4; r++) {
        float s = sc[nk][r] * SCL;
        if (enh) s = (pkw[nk] & eb_[r]) ? __builtin_fmaf(fabsf(s), 5.0f, s) : s;
        sc[nk][r] = (pkw[nk] & kb_[r]) ? NEGL : s;
      }
    float mx[4];
#pragma unroll
    for (int nk = 0; nk < 4; nk++)
      mx[nk] = fmaxf(fmaxf(sc[nk][0], sc[nk][1]), fmaxf(sc[nk][2], sc[nk][3]));
    float smax = fmaxf(fmaxf(mx[0], mx[1]), fmaxf(mx[2], mx[3]));
    smax = redmax_lg(smax);
    const bool defer = __all(smax - mrun <= 11.0f);
    const float mn = defer ? mrun : fmaxf(mrun, smax);
    float psum = 0.0f;
#pragma unroll
    for (int nk = 0; nk < 4; nk++)
#pragma unroll
      for (int r = 0; r < 4; r++) {
        float p = exp2_hw(sc[nk][r] - mn);
        sc[nk][r] = p;
        psum += p;
      }
    psum = redsum_lg(psum);
    if (defer) {
      lrun += psum;
    } else {
      const float so = exp2_hw(mrun - mn);
      lrun = lrun * so + psum;
      mrun = mn;
#pragma unroll
      for (int nd = 0; nd < 4; nd++)
#pragma unroll
        for (int r = 0; r < 4; r++) octx[nd][r] *= so;
    }
#pragma unroll
    for (int kk = 0; kk < 2; kk++) {
      u32 a0 = cvtpk(sc[2 * kk][0], sc[2 * kk][1]);
      u32 a1 = cvtpk(sc[2 * kk][2], sc[2 * kk][3]);
      u32 b0 = cvtpk(sc[2 * kk + 1][0], sc[2 * kk + 1][1]);
      u32 b1 = cvtpk(sc[2 * kk + 1][2], sc[2 * kk + 1][3]);
      plswap32(a0, b0);
      plswap32(a1, b1);
      plswap16(a0, b0);
      plswap16(a1, b1);
      u32x4 wv = {a0, a1, b0, b1};
      bf16x8 pfrag = __builtin_bit_cast(bf16x8, wv);
#pragma unroll
      for (int nd = 0; nd < 4; nd++) {
        bf16x8 vf = *(const bf16x8*)(bV + (nd * 16 + l15) * 64 + (c0 ^ (kk * 32)));
        octx[nd] = MFMA16(vf, pfrag, octx[nd]);
      }
    }
  }
  const float inv = 1.0f / lrun;
  u16* cb = ctx + (size_t)b * 1048576 + (size_t)(q0 + l15) * 1024 + h * 64 + lg * 4;
#pragma unroll
  for (int nd = 0; nd < 4; nd++) {
    *(ushort4*)(cb + nd * 16) = make_ushort4(f2bf(octx[nd][0] * inv), f2bf(octx[nd][1] * inv),
                                             f2bf(octx[nd][2] * inv), f2bf(octx[nd][3] * inv));
  }
}

extern "C" void kernel_launch(void* const* d_in, const int* in_sizes, int n_in,
                              void* d_out, int out_size, void* d_ws, size_t ws_size,
                              hipStream_t stream) {
  (void)in_sizes; (void)n_in; (void)out_size; (void)ws_size;
  const float* Q  = (const float*)d_in[0];
  const float* K  = (const float*)d_in[1];
  const float* V  = (const float*)d_in[2];
  const float* tok = (const float*)d_in[3];
  const float* st  = (const float*)d_in[4];
  const float* df  = (const float*)d_in[5];
  const float* cf  = (const float*)d_in[6];
  const int*   msk = (const int*)d_in[8];
  const float* Wq = (const float*)d_in[9];
  const float* bq = (const float*)d_in[10];
  const float* Wk = (const float*)d_in[11];
  const float* bk = (const float*)d_in[12];
  const float* Wv = (const float*)d_in[13];
  const float* bv = (const float*)d_in[14];
  const float* Wo = (const float*)d_in[15];
  const float* bo = (const float*)d_in[16];

  char* ws = (char*)d_ws;
  const size_t MB = 1ull << 20;
  u16* Qbf = (u16*)(ws);            // 3 x 8 MB, stride 8 MB (Q,K,V)
  u16* Wqb = (u16*)(ws + 24 * MB);  // 4 x 2 MB, stride 2 MB (Wq,Wk,Wv,Wo)
  u8*  pkQ = (u8*)(ws + 32 * MB);   // 4 MB packed masks
  u16* Qh  = (u16*)(ws + 36 * MB);  // 3 x 8 MB, stride 8 MB (Qh,Kh,VhT)
  u16* ctx = (u16*)(ws + 60 * MB);
  u16* Kbf = Qbf + 4194304;
  u16* Vbf = Qbf + 8388608;
  u16* Wkb = Wqb + 1048576;
  u16* Wvb = Wqb + 2097152;
  u16* Wob = Wqb + 3145728;

  prep_kernel<<<6656, 256, 0, stream>>>(
      (const float4*)Q, (const float4*)K, (const float4*)V, (const float4*)Wq, (const float4*)Wk,
      (const float4*)Wv, (const float4*)Wo, (ushort4*)Qbf, (ushort4*)Kbf, (ushort4*)Vbf,
      (ushort4*)Wqb, (ushort4*)Wkb, (ushort4*)Wvb, (ushort4*)Wob,
      (const float4*)tok, (const float4*)st, (const float4*)df, (const float4*)cf,
      (const int4*)msk, (u32*)pkQ);
  gemm_qkv<<<768, 256, 0, stream>>>(Qbf, Wqb, bq, bk, bv, Qh);
  attn_kernel<<<1024, 256, 0, stream>>>(Qh, Qh + 4194304, Qh + 8388608, pkQ, ctx);
  gemm_out<<<256, 256, 0, stream>>>(ctx, Wob, bo, (float*)d_out);
}

// Round 8
// 139.379 us; speedup vs baseline: 2.0368x; 1.0672x over previous
//
#include <hip/hip_runtime.h>
#include <stdint.h>

typedef unsigned short u16;
typedef unsigned int   u32;
typedef unsigned char  u8;
typedef __attribute__((ext_vector_type(4))) float f32x4;
typedef __attribute__((ext_vector_type(8))) __bf16 bf16x8;
typedef __attribute__((ext_vector_type(2))) unsigned int u32x2;
typedef __attribute__((ext_vector_type(4))) unsigned int u32x4;

#define MFMA16(a, b, c) __builtin_amdgcn_mfma_f32_16x16x32_bf16((a), (b), (c), 0, 0, 0)

__device__ __forceinline__ u16 f2bf(float f) {
  u32 u = __float_as_uint(f);
  return (u16)((u + 0x7fffu + ((u >> 16) & 1u)) >> 16);  // RNE
}

__device__ __forceinline__ void gl_lds16(const void* g, void* l) {
  __builtin_amdgcn_global_load_lds((const __attribute__((address_space(1))) u32*)g,
                                   (__attribute__((address_space(3))) u32*)l, 16, 0, 0);
}

__device__ __forceinline__ u32 cvtpk(float a, float b) {
  u32 r;
  asm("v_cvt_pk_bf16_f32 %0, %1, %2" : "=v"(r) : "v"(a), "v"(b));
  return r;
}

__device__ __forceinline__ float exp2_hw(float x) {  // v_exp_f32 = 2^x
  float r;
  asm("v_exp_f32 %0, %1" : "=v"(r) : "v"(x));
  return r;
}

__device__ __forceinline__ void plswap32(u32& x, u32& y) {
  u32x2 r = __builtin_amdgcn_permlane32_swap(x, y, false, false);
  x = r.x; y = r.y;
}
__device__ __forceinline__ void plswap16(u32& x, u32& y) {
  u32x2 r = __builtin_amdgcn_permlane16_swap(x, y, false, false);
  x = r.x; y = r.y;
}

__device__ __forceinline__ float redmax_lg(float v) {
  u32 x = __float_as_uint(v), y = x;
  plswap16(x, y);
  float m = fmaxf(__uint_as_float(x), __uint_as_float(y));
  u32 a = __float_as_uint(m), b = a;
  plswap32(a, b);
  return fmaxf(__uint_as_float(a), __uint_as_float(b));
}
__device__ __forceinline__ float redsum_lg(float v) {
  u32 x = __float_as_uint(v), y = x;
  plswap16(x, y);
  float m = __uint_as_float(x) + __uint_as_float(y);
  u32 a = __float_as_uint(m), b = a;
  plswap32(a, b);
  return __uint_as_float(a) + __uint_as_float(b);
}

// ---------------- mask pack (the only prep pass left) ----------------
// pack bits: 0=token 1=stmt 2=df 3=cf 4=mask!=0 5=token|!mask 6=stmt|!mask 7=!mask
// u32 word layout matches attn's per-wave coalesced dwordx4 read.
__device__ __forceinline__ u32 pbit(float t, float s, float d, float c, int m) {
  const u32 nm = (m == 0) ? 1u : 0u;
  u32 r = (t != 0.0f ? 1u : 0u) | (s != 0.0f ? 2u : 0u) | (d != 0.0f ? 4u : 0u) |
          (c != 0.0f ? 8u : 0u) | ((1u - nm) << 4);
  r |= (((t != 0.0f ? 1u : 0u) | nm) << 5) | (((s != 0.0f ? 1u : 0u) | nm) << 6) | (nm << 7);
  return r;
}

__global__ void __launch_bounds__(256) pack_kernel(const float4* __restrict__ tok, const float4* __restrict__ st,
                                                   const float4* __restrict__ df, const float4* __restrict__ cf,
                                                   const int4* __restrict__ msk, u32* __restrict__ pko) {
  const int i = blockIdx.x * 256 + threadIdx.x;  // float4 index over (b,q,k4)
  const int b = i >> 18, rem = i & 262143, q = rem >> 8, k4 = rem & 255;
  const int t = k4 >> 4, nk = (k4 >> 2) & 3, lg = k4 & 3;
  const u32 widx = ((u32)(b * 64 + (q >> 4)) * 16 + t) * 256 + (q & 15) * 16 + lg * 4 + nk;
  float4 vt = tok[i], vs = st[i], vd = df[i], vc = cf[i];
  int4 vm = msk[i];
  u32 b0 = pbit(vt.x, vs.x, vd.x, vc.x, vm.x);
  u32 b1 = pbit(vt.y, vs.y, vd.y, vc.y, vm.y);
  u32 b2 = pbit(vt.z, vs.z, vd.z, vc.z, vm.z);
  u32 b3 = pbit(vt.w, vs.w, vd.w, vc.w, vm.w);
  pko[widx] = b0 | (b1 << 8) | (b2 << 16) | (b3 << 24);
}

// ---------------- batched QKV projection GEMM, f32 inputs, reg-staged cvt ----------------
// grid = 768 (1D), XCD-local: l = (f&7)*96 + (f>>3).
// A = f32 activations (Q/K/V), B = f32 weights; cvt to bf16 in-reg during staging.
// z<2: write bf16 head-major  out[(b*16+h)*65536 + s*64 + d]
// z=2: write bf16 transposed  out[(b*16+h)*65536 + d*1024 + s]
__global__ void __launch_bounds__(256) gemm_qkv(const float* __restrict__ Qf, const float* __restrict__ Kf,
                                                const float* __restrict__ Vf, const float* __restrict__ Wqf,
                                                const float* __restrict__ Wkf, const float* __restrict__ Wvf,
                                                const float* __restrict__ bq, const float* __restrict__ bk,
                                                const float* __restrict__ bv, u16* __restrict__ Obase) {
  __shared__ u16 smA[128 * 32];
  __shared__ u16 smB[128 * 32];
  const int fb = blockIdx.x;
  const int lid = (fb & 7) * 96 + (fb >> 3);
  const int z = lid >> 8;
  const int m0 = ((lid & 255) >> 3) * 128;
  const int n0 = (lid & 7) * 128;
  const float* A = (z == 0) ? Qf : (z == 1) ? Kf : Vf;
  const float* W = (z == 0) ? Wqf : (z == 1) ? Wkf : Wvf;
  const float* bias = (z == 0) ? bq : (z == 1) ? bk : bv;
  u16* Out = Obase + (size_t)z * 4194304;
  const int t = threadIdx.x;
  const int w = t >> 6, l = t & 63;
  const int l15 = l & 15, lg = l >> 4;
  const int wr = w >> 1, wc = w & 1;
  f32x4 acc[4][4] = {};
  // staging: lane covers 8 f32 of rows {srow, srow+64}
  const int srow = w * 16 + (l >> 2);
  const int scol = (l & 3) * 8;
  const float* Ab = A + (size_t)(m0 + srow) * 1024 + scol;
  const float* Wb = W + (size_t)(n0 + srow) * 1024 + scol;
  u16* sA0 = smA + srow * 32 + scol;
  u16* sB0 = smB + srow * 32 + scol;

  float4 ra[2][2], rb[2][2];  // [row-pass][half]
#pragma unroll
  for (int p = 0; p < 2; p++)
#pragma unroll
    for (int hf = 0; hf < 2; hf++) {
      ra[p][hf] = *(const float4*)(Ab + p * 65536 + hf * 4);
      rb[p][hf] = *(const float4*)(Wb + p * 65536 + hf * 4);
    }

  for (int kk = 0; kk < 1024; kk += 32) {
    __syncthreads();  // all waves done reading LDS tile kk-32
#pragma unroll
    for (int p = 0; p < 2; p++) {
      u32x4 wa = {cvtpk(ra[p][0].x, ra[p][0].y), cvtpk(ra[p][0].z, ra[p][0].w),
                  cvtpk(ra[p][1].x, ra[p][1].y), cvtpk(ra[p][1].z, ra[p][1].w)};
      *(u32x4*)(sA0 + p * 2048) = wa;
      u32x4 wb2 = {cvtpk(rb[p][0].x, rb[p][0].y), cvtpk(rb[p][0].z, rb[p][0].w),
                   cvtpk(rb[p][1].x, rb[p][1].y), cvtpk(rb[p][1].z, rb[p][1].w)};
      *(u32x4*)(sB0 + p * 2048) = wb2;
    }
    __syncthreads();  // tile kk visible
    if (kk < 992) {   // prefetch next tile into regs; overlaps compute below
#pragma unroll
      for (int p = 0; p < 2; p++)
#pragma unroll
        for (int hf = 0; hf < 2; hf++) {
          ra[p][hf] = *(const float4*)(Ab + kk + 32 + p * 65536 + hf * 4);
          rb[p][hf] = *(const float4*)(Wb + kk + 32 + p * 65536 + hf * 4);
        }
    }
    bf16x8 af[4], bv_[4];
#pragma unroll
    for (int i = 0; i < 4; i++) af[i] = *(const bf16x8*)(smA + (wr * 64 + i * 16 + l15) * 32 + lg * 8);
#pragma unroll
    for (int i = 0; i < 4; i++) bv_[i] = *(const bf16x8*)(smB + (wc * 64 + i * 16 + l15) * 32 + lg * 8);
#pragma unroll
    for (int i = 0; i < 4; i++)
#pragma unroll
      for (int j = 0; j < 4; j++) acc[i][j] = MFMA16(af[i], bv_[j], acc[i][j]);
  }
#pragma unroll
  for (int j = 0; j < 4; j++) {
    const int n = n0 + wc * 64 + j * 16 + l15;
    const float bvj = bias[n];
#pragma unroll
    for (int i = 0; i < 4; i++) {
      const int mbase = m0 + wr * 64 + i * 16 + lg * 4;
      if (z < 2) {
#pragma unroll
        for (int r = 0; r < 4; r++) {
          const int m = mbase + r;
          Out[((size_t)((m >> 10) * 16 + (n >> 6)) << 16) + (size_t)(m & 1023) * 64 + (n & 63)] =
              f2bf(acc[i][j][r] + bvj);
        }
      } else {
        size_t off = ((size_t)((mbase >> 10) * 16 + (n >> 6)) << 16) + (size_t)(n & 63) * 1024 + (mbase & 1023);
        *(ushort4*)(Out + off) = make_ushort4(f2bf(acc[i][j][0] + bvj), f2bf(acc[i][j][1] + bvj),
                                              f2bf(acc[i][j][2] + bvj), f2bf(acc[i][j][3] + bvj));
      }
    }
  }
}

// ---------------- output projection GEMM: A = ctx bf16 (DMA), B = Wo f32 (reg-staged) ----------------
__global__ void __launch_bounds__(256) gemm_out(const u16* __restrict__ A, const float* __restrict__ W,
                                                const float* __restrict__ bias, float* __restrict__ Out) {
  __shared__ u16 smA[128 * 32];
  __shared__ u16 smB[128 * 32];
  const int fb = blockIdx.x;
  const int lid = (fb & 7) * 32 + (fb >> 3);
  const int m0 = (lid >> 3) * 128;
  const int n0 = (lid & 7) * 128;
  const int t = threadIdx.x;
  const int w = t >> 6, l = t & 63;
  const int l15 = l & 15, lg = l >> 4;
  const int wr = w >> 1, wc = w & 1;
  f32x4 acc[4][4] = {};
  const int srow = w * 16 + (l >> 2);
  const int scol = (l & 3) * 8;
  const u16* Ab = A + (size_t)(m0 + srow) * 1024 + scol;
  const float* Wb = W + (size_t)(n0 + srow) * 1024 + scol;
  u16* sA0 = smA + srow * 32 + scol;
  u16* sB0 = smB + srow * 32 + scol;

  float4 rb[2][2];
#pragma unroll
  for (int p = 0; p < 2; p++)
#pragma unroll
    for (int hf = 0; hf < 2; hf++) rb[p][hf] = *(const float4*)(Wb + p * 65536 + hf * 4);

  for (int kk = 0; kk < 1024; kk += 32) {
    __syncthreads();
    gl_lds16(Ab + kk, sA0);
    gl_lds16(Ab + kk + (size_t)64 * 1024, sA0 + 64 * 32);
#pragma unroll
    for (int p = 0; p < 2; p++) {
      u32x4 wb2 = {cvtpk(rb[p][0].x, rb[p][0].y), cvtpk(rb[p][0].z, rb[p][0].w),
                   cvtpk(rb[p][1].x, rb[p][1].y), cvtpk(rb[p][1].z, rb[p][1].w)};
      *(u32x4*)(sB0 + p * 2048) = wb2;
    }
    __syncthreads();  // drains DMA + LDS writes
    if (kk < 992) {
#pragma unroll
      for (int p = 0; p < 2; p++)
#pragma unroll
        for (int hf = 0; hf < 2; hf++) rb[p][hf] = *(const float4*)(Wb + kk + 32 + p * 65536 + hf * 4);
    }
    bf16x8 af[4], bv_[4];
#pragma unroll
    for (int i = 0; i < 4; i++) af[i] = *(const bf16x8*)(smA + (wr * 64 + i * 16 + l15) * 32 + lg * 8);
#pragma unroll
    for (int i = 0; i < 4; i++) bv_[i] = *(const bf16x8*)(smB + (wc * 64 + i * 16 + l15) * 32 + lg * 8);
#pragma unroll
    for (int i = 0; i < 4; i++)
#pragma unroll
      for (int j = 0; j < 4; j++) acc[i][j] = MFMA16(af[i], bv_[j], acc[i][j]);
  }
#pragma unroll
  for (int j = 0; j < 4; j++) {
    const int n = n0 + wc * 64 + j * 16 + l15;
    const float bvj = bias[n];
#pragma unroll
    for (int i = 0; i < 4; i++) {
      const int mbase = m0 + wr * 64 + i * 16 + lg * 4;
#pragma unroll
      for (int r = 0; r < 4; r++) Out[(size_t)(mbase + r) * 1024 + n] = acc[i][j][r] + bvj;
    }
  }
}

// ---------------- flash attention: LDS-staged K/V, log2-domain softmax, T13 defer ----------------
__global__ void __launch_bounds__(256) attn_kernel(const u16* __restrict__ Qp, const u16* __restrict__ Kp,
                                                   const u16* __restrict__ Vt, const u8* __restrict__ pack,
                                                   u16* __restrict__ ctx) {
  __shared__ u16 smK[2][4096];
  __shared__ u16 smV[2][4096];
  const float SCL  = 0.18033688011112042f;  // 0.125 * log2(e)
  const float NEGL = -1.44269504e9f;        // -1e9 * log2(e)
  const int tid = threadIdx.x;
  const int w = tid >> 6, l = tid & 63;
  const int l15 = l & 15, lg = l >> 4;
  const int f = blockIdx.x;
  const int swz = (f & 7) * 128 + (f >> 3);  // bijective XCD swizzle
  const int bh = swz >> 4, bx = swz & 15;
  const int b = bh >> 4, h = bh & 15;
  const int q0 = bx * 64 + w * 16;
  const bool enh = (h >= 8 && h < 12);
  const u32 kbit = (h < 4) ? 0x20u : (h < 8) ? 0x40u : 0x80u;
  const u32 ebit = (h < 10) ? 0x04u : 0x08u;
  const u32 kb_[4] = {kbit, kbit << 8, kbit << 16, kbit << 24};
  const u32 eb_[4] = {ebit, ebit << 8, ebit << 16, ebit << 24};
  const size_t hb = (size_t)bh << 16;

  bf16x8 qf[2];
#pragma unroll
  for (int ks = 0; ks < 2; ks++)
    qf[ks] = *(const bf16x8*)(Qp + hb + (size_t)(q0 + l15) * 64 + ks * 32 + lg * 8);

  const int srow = w * 16 + (l >> 3);
  const int schunk = (l & 7) ^ (l >> 3);
  const u16* Ksrc = Kp + hb + (size_t)srow * 64 + schunk * 8;
  const u16* Vsrc = Vt + hb + (size_t)srow * 1024 + schunk * 8;
  const int c0 = (lg ^ (l15 & 7)) * 8;
  const u8* pkq = pack + ((size_t)((b * 64 + bx * 4 + w) * 16)) * 1024 + (l15 * 4 + lg) * 16;

  gl_lds16(Ksrc, &smK[0][w * 1024]);
  gl_lds16(Ksrc + 512, &smK[0][w * 1024 + 512]);
  gl_lds16(Vsrc, &smV[0][w * 1024]);
  gl_lds16(Vsrc + 8192, &smV[0][w * 1024 + 512]);
  uint4 pk_next = *(const uint4*)(pkq);

  f32x4 octx[4] = {};
  float mrun = -3.0e38f, lrun = 0.0f;

  for (int t = 0; t < 16; t++) {
    __syncthreads();
    const uint4 pkc = pk_next;
    if (t < 15) {
      const int kb = (t + 1) * 64;
      const int nb = (t + 1) & 1;
      gl_lds16(Ksrc + (size_t)kb * 64, &smK[nb][w * 1024]);
      gl_lds16(Ksrc + (size_t)kb * 64 + 512, &smK[nb][w * 1024 + 512]);
      gl_lds16(Vsrc + kb, &smV[nb][w * 1024]);
      gl_lds16(Vsrc + kb + 8192, &smV[nb][w * 1024 + 512]);
      pk_next = *(const uint4*)(pkq + (t + 1) * 1024);
    }
    const u16* bK = smK[t & 1];
    const u16* bV = smV[t & 1];
    f32x4 sc[4];
#pragma unroll
    for (int nk = 0; nk < 4; nk++) {
      const u16* kr = bK + (nk * 16 + l15) * 64;
      bf16x8 kf0 = *(const bf16x8*)(kr + c0);
      bf16x8 kf1 = *(const bf16x8*)(kr + (c0 ^ 32));
      f32x4 z = {0.0f, 0.0f, 0.0f, 0.0f};
      z = MFMA16(kf0, qf[0], z);
      z = MFMA16(kf1, qf[1], z);
      sc[nk] = z;
    }
    const u32 pkw[4] = {pkc.x, pkc.y, pkc.z, pkc.w};
#pragma unroll
    for (int nk = 0; nk < 4; nk++)
#pragma unroll
      for (int r = 0; r < 4; r++) {
        float s = sc[nk][r] * SCL;
        if (enh) s = (pkw[nk] & eb_[r]) ? __builtin_fmaf(fabsf(s), 5.0f, s) : s;
        sc[nk][r] = (pkw[nk] & kb_[r]) ? NEGL : s;
      }
    float mx[4];
#pragma unroll
    for (int nk = 0; nk < 4; nk++)
      mx[nk] = fmaxf(fmaxf(sc[nk][0], sc[nk][1]), fmaxf(sc[nk][2], sc[nk][3]));
    float smax = fmaxf(fmaxf(mx[0], mx[1]), fmaxf(mx[2], mx[3]));
    smax = redmax_lg(smax);
    const bool defer = __all(smax - mrun <= 11.0f);
    const float mn = defer ? mrun : fmaxf(mrun, smax);
    float psum = 0.0f;
#pragma unroll
    for (int nk = 0; nk < 4; nk++)
#pragma unroll
      for (int r = 0; r < 4; r++) {
        float p = exp2_hw(sc[nk][r] - mn);
        sc[nk][r] = p;
        psum += p;
      }
    psum = redsum_lg(psum);
    if (defer) {
      lrun += psum;
    } else {
      const float so = exp2_hw(mrun - mn);
      lrun = lrun * so + psum;
      mrun = mn;
#pragma unroll
      for (int nd = 0; nd < 4; nd++)
#pragma unroll
        for (int r = 0; r < 4; r++) octx[nd][r] *= so;
    }
#pragma unroll
    for (int kk = 0; kk < 2; kk++) {
      u32 a0 = cvtpk(sc[2 * kk][0], sc[2 * kk][1]);
      u32 a1 = cvtpk(sc[2 * kk][2], sc[2 * kk][3]);
      u32 b0 = cvtpk(sc[2 * kk + 1][0], sc[2 * kk + 1][1]);
      u32 b1 = cvtpk(sc[2 * kk + 1][2], sc[2 * kk + 1][3]);
      plswap32(a0, b0);
      plswap32(a1, b1);
      plswap16(a0, b0);
      plswap16(a1, b1);
      u32x4 wv = {a0, a1, b0, b1};
      bf16x8 pfrag = __builtin_bit_cast(bf16x8, wv);
#pragma unroll
      for (int nd = 0; nd < 4; nd++) {
        bf16x8 vf = *(const bf16x8*)(bV + (nd * 16 + l15) * 64 + (c0 ^ (kk * 32)));
        octx[nd] = MFMA16(vf, pfrag, octx[nd]);
      }
    }
  }
  const float inv = 1.0f / lrun;
  u16* cb = ctx + (size_t)b * 1048576 + (size_t)(q0 + l15) * 1024 + h * 64 + lg * 4;
#pragma unroll
  for (int nd = 0; nd < 4; nd++) {
    *(ushort4*)(cb + nd * 16) = make_ushort4(f2bf(octx[nd][0] * inv), f2bf(octx[nd][1] * inv),
                                             f2bf(octx[nd][2] * inv), f2bf(octx[nd][3] * inv));
  }
}

extern "C" void kernel_launch(void* const* d_in, const int* in_sizes, int n_in,
                              void* d_out, int out_size, void* d_ws, size_t ws_size,
                              hipStream_t stream) {
  (void)in_sizes; (void)n_in; (void)out_size; (void)ws_size;
  const float* Q  = (const float*)d_in[0];
  const float* K  = (const float*)d_in[1];
  const float* V  = (const float*)d_in[2];
  const float* tok = (const float*)d_in[3];
  const float* st  = (const float*)d_in[4];
  const float* df  = (const float*)d_in[5];
  const float* cf  = (const float*)d_in[6];
  const int*   msk = (const int*)d_in[8];
  const float* Wq = (const float*)d_in[9];
  const float* bq = (const float*)d_in[10];
  const float* Wk = (const float*)d_in[11];
  const float* bk = (const float*)d_in[12];
  const float* Wv = (const float*)d_in[13];
  const float* bv = (const float*)d_in[14];
  const float* Wo = (const float*)d_in[15];
  const float* bo = (const float*)d_in[16];

  char* ws = (char*)d_ws;
  const size_t MB = 1ull << 20;
  u8*  pkQ = (u8*)(ws);             // 4 MB packed masks
  u16* Qh  = (u16*)(ws + 4 * MB);   // 3 x 8 MB, stride 8 MB (Qh,Kh,VhT)
  u16* ctx = (u16*)(ws + 28 * MB);  // 8 MB

  pack_kernel<<<4096, 256, 0, stream>>>((const float4*)tok, (const float4*)st, (const float4*)df,
                                        (const float4*)cf, (const int4*)msk, (u32*)pkQ);
  gemm_qkv<<<768, 256, 0, stream>>>(Q, K, V, Wq, Wk, Wv, bq, bk, bv, Qh);
  attn_kernel<<<1024, 256, 0, stream>>>(Qh, Qh + 4194304, Qh + 8388608, pkQ, ctx);
  gemm_out<<<256, 256, 0, stream>>>(ctx, Wo, bo, (float*)d_out);
}